// Round 12
// baseline (288.419 us; speedup 1.0000x reference)
//
#include <hip/hip_runtime.h>
#include <math.h>

#define NPG   200                 // nodes per graph
#define HDIM  128
#define NG    256
#define NT_T  (NG * NPG)          // 51200
#define EPG_  3200
#define E_T   (NG * EPG_)         // 819200
#define KP1   224                 // layer-1 K (200) padded to mult of 32 (W pitch)
#define TTP   232                 // Tt LDS pitch (shorts): s-pad [200,224) ZEROED
#define HP    136                 // h LDS pitch (shorts)
#define W1SZ  (256 * KP1)
#define W2SZ  (256 * HDIM)

#define XSTR1 40960               // X / A' slab stride, shorts (81,920 B; data 80,000)

// LDS arena (bytes):
//   [0,80000)        X (phase2-L1) -> Tt(59,392)+zsum -> h(54,400) -> Tt2
//   [59392,60416)    zsum1[128]|zsum2[128] f32 (inside dead-X region)
//   [80000,160000)   Af bf16, pitch 200 shorts, PERSISTENT across both AGGs
//   [160000,160064)  zeroed tail (Af row-199 chunk overruns land here)
#define ZSOFF3 59392
#define AFOFF  80000
#define ARENA_SZ3 160064

// prep-kernel grid partition
#define NB_ADJ (2 * NG)                       // 512
#define NB_CX  (2 * NG * 5120 / 256)          // 10240
#define NB_CW  ((2 * (W1SZ + W2SZ)) / 256)    // 704
#define NB_PREP (NB_ADJ + NB_CX + NB_CW)

typedef short short8 __attribute__((ext_vector_type(8)));
typedef float f32x4  __attribute__((ext_vector_type(4)));

__device__ __forceinline__ unsigned short f2bf(float f) {
    union { float f; unsigned int u; } v; v.f = f;
    unsigned int u = v.u;
    u += 0x7FFFu + ((u >> 16) & 1u);       // RNE
    return (unsigned short)(u >> 16);
}

// ---------------------------------------------------------------------------
// Prep: [0,512) adjacency -> A' bf16 slabs (pitch 200, stride 40,960 shorts,
// pad zeroed); [512,10752) X fp32 -> bf16 slabs; [10752,11456) W convert.
// (unchanged from round 10/11)
// ---------------------------------------------------------------------------
__global__ __launch_bounds__(256) void prep_kernel(
        const int* __restrict__ sc_ei, const int* __restrict__ fc_ei,
        const float* __restrict__ sc_x, const float* __restrict__ fc_x,
        const float* __restrict__ s1r, const float* __restrict__ s1o,
        const float* __restrict__ f1r, const float* __restrict__ f1o,
        const float* __restrict__ s2r, const float* __restrict__ s2o,
        const float* __restrict__ f2r, const float* __restrict__ f2o,
        unsigned short* __restrict__ A, unsigned short* __restrict__ xb,
        unsigned short* __restrict__ wb) {
    const int b = blockIdx.x, t = threadIdx.x;

    if (b < NB_ADJ) {
        __shared__ unsigned int cnt[10000];    // 200*200 u8 counters in u32
        __shared__ float invdeg[200];
        const int branch = b >> 8, g = b & 255;
        const int* ei = branch ? fc_ei : sc_ei;

        for (int i = t; i < 10000; i += 256) cnt[i] = 0u;
        __syncthreads();
        const int ebase = g * EPG_;
        for (int i = t; i < EPG_; i += 256) {
            int src = ei[ebase + i];
            int dst = ei[E_T + ebase + i];
            int idx = (dst - g * NPG) * NPG + (src - g * NPG);
            atomicAdd(&cnt[idx >> 2], 1u << ((idx & 3) * 8));
        }
        __syncthreads();
        if (t < NPG) {
            unsigned int s = 0;
            for (int w = 0; w < 50; ++w) {
                unsigned int v = cnt[t * 50 + w];
                s += (v & 0xFFu) + ((v >> 8) & 0xFFu) + ((v >> 16) & 0xFFu) + ((v >> 24) & 0xFFu);
            }
            invdeg[t] = 1.0f / fmaxf((float)s, 1.0f);
        }
        __syncthreads();
        unsigned short* Ag = A + ((size_t)branch * NG + g) * XSTR1;
        for (int q = t; q < 10000; q += 256) {
            int row = q / 50;
            int c4  = (q - row * 50) * 4;
            float inv = invdeg[row];
            unsigned int w = cnt[q];             // word holds cols c4..c4+3
            ushort4 o;
            unsigned short* po = (unsigned short*)&o;
#pragma unroll
            for (int j = 0; j < 4; ++j)
                po[j] = f2bf((float)((w >> (j * 8)) & 0xFFu) * inv);
            *(ushort4*)&Ag[row * 200 + c4] = o;
        }
        // zero slab pad [40000, 40960) shorts
        if (t < 240) {
            ushort4 zo = {0, 0, 0, 0};
            *(ushort4*)&Ag[40000 + t * 4] = zo;
        }
    } else if (b < NB_ADJ + NB_CX) {
        // ---- X fp32 [node,200] -> bf16 slabs pitch 200, stride 40960, pad zeroed
        int c = (b - NB_ADJ) * 256 + t;          // 0 .. 2*256*5120-1
        int slab = c / 5120;                     // branch*256 + g
        int ci = c - slab * 5120;                // chunk (8 shorts) within slab
        uint4 o;
        if (ci < 5000) {
            int n  = ci / 25;                    // node within graph
            int k8 = ci - n * 25;
            int branch = slab >> 8, g = slab & 255;
            const float* x = branch ? fc_x : sc_x;
            const float* p = x + ((size_t)g * NPG + n) * 200 + k8 * 8;
            float4 a  = *(const float4*)p;
            float4 bb = *(const float4*)(p + 4);
            o.x = (unsigned)f2bf(a.x) | ((unsigned)f2bf(a.y) << 16);
            o.y = (unsigned)f2bf(a.z) | ((unsigned)f2bf(a.w) << 16);
            o.z = (unsigned)f2bf(bb.x) | ((unsigned)f2bf(bb.y) << 16);
            o.w = (unsigned)f2bf(bb.z) | ((unsigned)f2bf(bb.w) << 16);
        } else {
            o.x = o.y = o.z = o.w = 0u;          // slab pad
        }
        *(uint4*)&xb[(size_t)slab * XSTR1 + (size_t)ci * 8] = o;
    } else {
        // ---- weights -> packed W^T bf16 [br0L1|br1L1|br0L2|br1L2], rel|root rows
        int idx = (b - NB_ADJ - NB_CX) * 256 + t;
        float v = 0.0f;
        if (idx < 2 * W1SZ) {
            int branch = idx / W1SZ, rem = idx - branch * W1SZ;
            int c = rem / KP1, k = rem - c * KP1;
            const float* wr = branch ? f1r : s1r;
            const float* wo = branch ? f1o : s1o;
            if (k < 200) v = (c < 128) ? wr[(size_t)k * 128 + c] : wo[(size_t)k * 128 + (c - 128)];
        } else {
            int i2 = idx - 2 * W1SZ;
            int branch = i2 / W2SZ, rem = i2 - branch * W2SZ;
            int c = rem / HDIM, k = rem - c * HDIM;
            const float* wr = branch ? f2r : s2r;
            const float* wo = branch ? f2o : s2o;
            v = (c < 128) ? wr[(size_t)k * 128 + c] : wo[(size_t)k * 128 + (c - 128)];
        }
        wb[idx] = f2bf(v);
    }
}

// ---------------------------------------------------------------------------
// Round-19: round-18 body with the launch-bounds spill fix.
//
// Evidence (r11): __launch_bounds__(1024, 1) let the allocator target the
// 64-VGPR occupancy step -> 137 MB scratch WRITE + 111 MB FETCH (spill
// round-trips) -> 91 µs.  The occupancy goal itself landed (21.8 -> 40.6%).
// Fix: __launch_bounds__(1024, 4): 4 waves/EU x 4 EU = 16 waves = exactly
// one block/CU -> VGPR cap 128.  Per-thread needs ~110 (56 acc + 28 xf +
// addressing) -> fits, no spill.  Body otherwise identical to r11
// (bitwise-identical output).
//   F1 vmcnt(5)+bar     X landed (5 Af loads in flight)
//   F2 vmcnt(0)lgkm+bar X dead, Af landed
//   F3..F8              as r10/r11
// ---------------------------------------------------------------------------
__global__ __launch_bounds__(1024, 4) void fused_kernel(
        const unsigned short* __restrict__ Xb,
        const unsigned short* __restrict__ Wall,
        const unsigned short* __restrict__ Ab,
        const float* __restrict__ s1b, const float* __restrict__ f1b,
        const float* __restrict__ s2b, const float* __restrict__ f2b,
        float* __restrict__ z) {
    __shared__ __attribute__((aligned(16))) char arena[ARENA_SZ3];

    const int tid = threadIdx.x;
    const int lane = tid & 63, wid = tid >> 6;   // 16 waves
    const int l15 = lane & 15, quad = lane >> 4;
    const int ms = wid & 1, ns = wid >> 1;       // node half x channel eighth

    const int g = blockIdx.x & 255, branch = blockIdx.x >> 8;

    const unsigned short* Xg = Xb + ((size_t)branch * NG + g) * XSTR1;
    const unsigned short* Ag = Ab + ((size_t)branch * NG + g) * XSTR1;
    const unsigned short* W1 = Wall + (size_t)branch * W1SZ;
    const unsigned short* W2 = Wall + (size_t)2 * W1SZ + (size_t)branch * W2SZ;

    // zero the 64B tail (Af row-199 overrun target) — must be finite
    if (tid < 16) *(unsigned int*)(arena + 160000 + tid * 4) = 0u;

    // ---- stage X slab then A' slab (5 + 5 uniform 16B loads per thread;
    // the j=4 tail overlaps [3976,4096) with identical bytes — benign)
    {
        __attribute__((address_space(3))) char* lx =
            (__attribute__((address_space(3))) char*)&arena[0];
        for (int j = 0; j <= 4; ++j) {
            int i = (j < 4) ? (j * 1024 + tid) : (5000 - 1024 + tid);
            const char* gp = (const char*)Xg + (size_t)i * 16;
            __builtin_amdgcn_global_load_lds(
                (const __attribute__((address_space(1))) unsigned int*)gp,
                (__attribute__((address_space(3))) unsigned int*)(lx + (size_t)i * 16),
                16, 0, 0);
        }
        __builtin_amdgcn_sched_barrier(0);
        __attribute__((address_space(3))) char* la =
            (__attribute__((address_space(3))) char*)&arena[AFOFF];
        for (int j = 0; j <= 4; ++j) {
            int i = (j < 4) ? (j * 1024 + tid) : (5000 - 1024 + tid);
            const char* gp = (const char*)Ag + (size_t)i * 16;
            __builtin_amdgcn_global_load_lds(
                (const __attribute__((address_space(1))) unsigned int*)gp,
                (__attribute__((address_space(3))) unsigned int*)(la + (size_t)i * 16),
                16, 0, 0);
        }
    }

    int nrow[7];
#pragma unroll
    for (int mt = 0; mt < 7; ++mt) {
        int s = (ms * 7 + mt) * 16 + l15;
        nrow[mt] = (s > NPG - 1) ? (NPG - 1) : s;   // clamp; killed downstream
    }
    const int crow = ns * 16 + l15;                 // this wave's channel row 0..127

    // barrier-free agg: acc += Tt x Af (Af pitch 200, overruns finite)
    auto AGG = [&](f32x4 (&acc)[7]) {
        const short* Tt = (const short*)arena;
        const short* Af = (const short*)(arena + AFOFF);
#pragma unroll
        for (int ki = 0; ki < 7; ++ki) {
            const int k0 = ki * 32 + quad * 8;
            short8 tf = *(const short8*)&Tt[crow * TTP + k0];
            short8 afr[7];
#pragma unroll
            for (int dt = 0; dt < 7; ++dt)
                afr[dt] = *(const short8*)&Af[nrow[dt] * 200 + k0];
#pragma unroll
            for (int dt = 0; dt < 7; ++dt)
                acc[dt] = __builtin_amdgcn_mfma_f32_16x16x32_bf16(
                    tf, afr[dt], acc[dt], 0, 0, 0);
        }
    };

    // T write: acc[m=s] -> Tt [c 128][s pad 232] at arena[0], s>=200 zero
    auto WRITE_T = [&](f32x4 (&acc)[7]) {
        short* Tt = (short*)arena;
#pragma unroll
        for (int mt = 0; mt < 7; ++mt) {
            int s0 = (ms * 7 + mt) * 16 + quad * 4;
            ushort4 o;
            unsigned short* po = (unsigned short*)&o;
#pragma unroll
            for (int r = 0; r < 4; ++r)
                po[r] = (s0 + r < NPG) ? f2bf(acc[mt][r]) : (unsigned short)0;
            *(ushort4*)&Tt[crow * TTP + s0] = o;
        }
    };

    // ================= L1 =================
    {
        f32x4 accT[7], accH[7];
#pragma unroll
        for (int mt = 0; mt < 7; ++mt)
#pragma unroll
            for (int r = 0; r < 4; ++r) { accT[mt][r] = 0.0f; accH[mt][r] = 0.0f; }

        // F1: X landed (5 Af loads still in flight)
        asm volatile("s_waitcnt vmcnt(5)\n\ts_barrier" ::: "memory");

        // phase 2: merged transform + root (X from LDS pitch 400B, W1 direct)
#pragma unroll
        for (int ki = 0; ki < 7; ++ki) {
            int cch = ki * 4 + quad;
            if (cch > 24) cch = 24;                 // never read past staged row
            short8 xf[7];
#pragma unroll
            for (int mt = 0; mt < 7; ++mt)
                xf[mt] = *(const short8*)(arena + nrow[mt] * 400 + cch * 16);
            const int kb = ki * 32 + quad * 8;
            short8 wr = *(const short8*)&W1[(size_t)crow * KP1 + kb];
            short8 wo = *(const short8*)&W1[(size_t)(128 + crow) * KP1 + kb];
#pragma unroll
            for (int mt = 0; mt < 7; ++mt)
                accT[mt] = __builtin_amdgcn_mfma_f32_16x16x32_bf16(
                    xf[mt], wr, accT[mt], 0, 0, 0);
#pragma unroll
            for (int mt = 0; mt < 7; ++mt)
                accH[mt] = __builtin_amdgcn_mfma_f32_16x16x32_bf16(
                    wo, xf[mt], accH[mt], 0, 0, 0);
        }

        // F2: X dead everywhere; Af fully landed
        asm volatile("s_waitcnt vmcnt(0) lgkmcnt(0)\n\ts_barrier" ::: "memory");

        WRITE_T(accT);                              // Tt over dead X
        if (tid < 256) ((float*)(arena + ZSOFF3))[tid] = 0.0f;   // zsum1|zsum2
        __syncthreads();                            // F3: Tt + zsum visible

        AGG(accH);                                  // barrier-free
        __syncthreads();                            // F4: Tt dead (h overwrites)

        // epilogue: relu+bias, pool -> zsum1, h -> LDS [0,54400) pitch 136
        const float* brel = branch ? f1b : s1b;
        float* zs1 = (float*)(arena + ZSOFF3);
        short* hb = (short*)arena;
        {
            const int c0 = ns * 16 + quad * 4;
            float bb[4], part[4];
#pragma unroll
            for (int r = 0; r < 4; ++r) { bb[r] = brel[c0 + r]; part[r] = 0.0f; }
#pragma unroll
            for (int dt = 0; dt < 7; ++dt) {
                const int d = (ms * 7 + dt) * 16 + l15;
                if (d < NPG) {
                    ushort4 o;
                    unsigned short* po = (unsigned short*)&o;
#pragma unroll
                    for (int r = 0; r < 4; ++r) {
                        float v = fmaxf(accH[dt][r] + bb[r], 0.0f);
                        part[r] += v;
                        po[r] = f2bf(v);
                    }
                    *(ushort4*)&hb[d * HP + c0] = o;
                }
            }
#pragma unroll
            for (int r = 0; r < 4; ++r) {
                float v = part[r];
                v += __shfl_xor(v, 1);
                v += __shfl_xor(v, 2);
                v += __shfl_xor(v, 4);
                v += __shfl_xor(v, 8);
                if (l15 == 0) atomicAdd(&zs1[c0 + r], v);
            }
        }
        __syncthreads();                            // F5: h + zsum1 final
        if (tid < 128)
            z[(size_t)g * 512 + branch * 256 + 0 + tid] =
                zs1[tid] * (branch ? 1.0f : (1.0f / 200.0f));
    }

    // ================= L2 =================
    {
        f32x4 accT[7], accH[7];
#pragma unroll
        for (int mt = 0; mt < 7; ++mt)
#pragma unroll
            for (int r = 0; r < 4; ++r) { accT[mt][r] = 0.0f; accH[mt][r] = 0.0f; }

        // phase 2: h (LDS pitch 272B, 16 real chunks) x W2 (direct)
#pragma unroll
        for (int ki = 0; ki < 4; ++ki) {
            short8 xf[7];
#pragma unroll
            for (int mt = 0; mt < 7; ++mt)
                xf[mt] = *(const short8*)(arena + nrow[mt] * (HP * 2) + (ki * 4 + quad) * 16);
            const int kb = ki * 32 + quad * 8;
            short8 wr = *(const short8*)&W2[(size_t)crow * HDIM + kb];
            short8 wo = *(const short8*)&W2[(size_t)(128 + crow) * HDIM + kb];
#pragma unroll
            for (int mt = 0; mt < 7; ++mt)
                accT[mt] = __builtin_amdgcn_mfma_f32_16x16x32_bf16(
                    xf[mt], wr, accT[mt], 0, 0, 0);
#pragma unroll
            for (int mt = 0; mt < 7; ++mt)
                accH[mt] = __builtin_amdgcn_mfma_f32_16x16x32_bf16(
                    wo, xf[mt], accH[mt], 0, 0, 0);
        }

        __syncthreads();   // F6: h dead
        WRITE_T(accT);     // Tt2 overwrites h/Tt region
        __syncthreads();   // F7: Tt2 visible

        AGG(accH);         // barrier-free; Af still resident

        // epilogue: pool only -> zsum2
        const float* brel = branch ? f2b : s2b;
        float* zs2 = (float*)(arena + ZSOFF3 + 512);
        {
            const int c0 = ns * 16 + quad * 4;
            float bb[4], part[4];
#pragma unroll
            for (int r = 0; r < 4; ++r) { bb[r] = brel[c0 + r]; part[r] = 0.0f; }
#pragma unroll
            for (int dt = 0; dt < 7; ++dt) {
                const int d = (ms * 7 + dt) * 16 + l15;
                if (d < NPG) {
#pragma unroll
                    for (int r = 0; r < 4; ++r)
                        part[r] += fmaxf(accH[dt][r] + bb[r], 0.0f);
                }
            }
#pragma unroll
            for (int r = 0; r < 4; ++r) {
                float v = part[r];
                v += __shfl_xor(v, 1);
                v += __shfl_xor(v, 2);
                v += __shfl_xor(v, 4);
                v += __shfl_xor(v, 8);
                if (l15 == 0) atomicAdd(&zs2[c0 + r], v);
            }
        }
        __syncthreads();   // F8: zsum2 complete
        if (tid < 128)
            z[(size_t)g * 512 + branch * 256 + 128 + tid] =
                zs2[tid] * (branch ? 1.0f : (1.0f / 200.0f));
    }
}

// ---------------------------------------------------------------------------
// MLP head (fp32): z[512] -> relu(lin1)[128] -> relu(lin2)[64] -> lin3[2]
// -> log_softmax. One block per graph.  (unchanged)
// ---------------------------------------------------------------------------
__global__ __launch_bounds__(128) void mlp_kernel(const float* __restrict__ z,
                                                  const float* __restrict__ w1, const float* __restrict__ b1,
                                                  const float* __restrict__ w2, const float* __restrict__ b2,
                                                  const float* __restrict__ w3, const float* __restrict__ b3,
                                                  float* __restrict__ out) {
    __shared__ float zs[512];
    __shared__ float l1[128];
    __shared__ float l2[64];
    __shared__ float logits[2];
    int g = blockIdx.x, t = threadIdx.x;

#pragma unroll
    for (int i = 0; i < 4; ++i) zs[t + 128 * i] = z[(size_t)g * 512 + t + 128 * i];
    __syncthreads();

    float s = b1[t];
#pragma unroll 8
    for (int k = 0; k < 512; ++k) s = fmaf(zs[k], w1[k * 128 + t], s);
    l1[t] = fmaxf(s, 0.0f);
    __syncthreads();

    if (t < 64) {
        float s2 = b2[t];
#pragma unroll 8
        for (int k = 0; k < 128; ++k) s2 = fmaf(l1[k], w2[k * 64 + t], s2);
        l2[t] = fmaxf(s2, 0.0f);
    }
    __syncthreads();

    if (t < 2) {
        float s3 = b3[t];
        for (int k = 0; k < 64; ++k) s3 = fmaf(l2[k], w3[k * 2 + t], s3);
        logits[t] = s3;
    }
    __syncthreads();

    if (t < 2) {
        float m = fmaxf(logits[0], logits[1]);
        float lse = m + logf(expf(logits[0] - m) + expf(logits[1] - m));
        out[(size_t)g * 2 + t] = logits[t] - lse;
    }
}

// ---------------------------------------------------------------------------
extern "C" void kernel_launch(void* const* d_in, const int* in_sizes, int n_in,
                              void* d_out, int out_size, void* d_ws, size_t ws_size,
                              hipStream_t stream) {
    const float* sc_x = (const float*)d_in[0];
    const float* fc_x = (const float*)d_in[1];
    const int* sc_ei  = (const int*)d_in[2];
    const int* fc_ei  = (const int*)d_in[3];
    const float* sc1_wrel = (const float*)d_in[5];
    const float* sc1_brel = (const float*)d_in[6];
    const float* sc1_wroot = (const float*)d_in[7];
    const float* sc2_wrel = (const float*)d_in[8];
    const float* sc2_brel = (const float*)d_in[9];
    const float* sc2_wroot = (const float*)d_in[10];
    const float* fc1_wrel = (const float*)d_in[11];
    const float* fc1_brel = (const float*)d_in[12];
    const float* fc1_wroot = (const float*)d_in[13];
    const float* fc2_wrel = (const float*)d_in[14];
    const float* fc2_brel = (const float*)d_in[15];
    const float* fc2_wroot = (const float*)d_in[16];
    const float* lin1_w = (const float*)d_in[17];
    const float* lin1_b = (const float*)d_in[18];
    const float* lin2_w = (const float*)d_in[19];
    const float* lin2_b = (const float*)d_in[20];
    const float* lin3_w = (const float*)d_in[21];
    const float* lin3_b = (const float*)d_in[22];

    // Workspace: Xb (bf16 slabs) | Ab (bf16 A' slabs) | Wb | z   (~85 MB)
    unsigned short* Xb = (unsigned short*)d_ws;                  // 2*256*40960
    unsigned short* Ab = Xb + (size_t)2 * NG * XSTR1;            // 2*256*40960
    unsigned short* Wb = Ab + (size_t)2 * NG * XSTR1;            // 2*(W1SZ+W2SZ)
    float* z = (float*)(Wb + (size_t)2 * (W1SZ + W2SZ));         // 256*512 fp32

    prep_kernel<<<NB_PREP, 256, 0, stream>>>(
        sc_ei, fc_ei, sc_x, fc_x,
        sc1_wrel, sc1_wroot, fc1_wrel, fc1_wroot,
        sc2_wrel, sc2_wroot, fc2_wrel, fc2_wroot,
        Ab, Xb, Wb);

    fused_kernel<<<512, 1024, 0, stream>>>(
        Xb, Wb, Ab, sc1_brel, fc1_brel, sc2_brel, fc2_brel, z);

    mlp_kernel<<<NG, 128, 0, stream>>>(z, lin1_w, lin1_b, lin2_w, lin2_b,
                                       lin3_w, lin3_b, (float*)d_out);
}

// Round 13
// 256.999 us; speedup vs baseline: 1.1223x; 1.1223x over previous
//
#include <hip/hip_runtime.h>
#include <math.h>

#define NPG   200                 // nodes per graph
#define HDIM  128
#define NG    256
#define NT_T  (NG * NPG)          // 51200
#define EPG_  3200
#define E_T   (NG * EPG_)         // 819200
#define KP1   224                 // layer-1 K (200) padded to mult of 32 (W pitch)
#define TTP   232                 // Tt LDS pitch (shorts): 29 chunks (mod8=5, spread)
#define AFP   232                 // A'full LDS pitch (shorts): same spread
#define HP    136                 // h LDS pitch (shorts): 17 chunks (mod8=1, spread)
#define W1SZ  (256 * KP1)
#define W2SZ  (256 * HDIM)

#define XSTR1 40960               // X slab stride, shorts (81,920 B; data 80,000)
#define CBLOB 40960               // cnt blob bytes/slab: 40,000 cnt + 800 invdeg + 160 pad

// LDS arena (bytes): Af [0,92800) over dead X | Tt/h [92800,152192) over dead
// cnt | cnt [112000,152960) | zsum [152960,153984)
#define TT2OFF 92800
#define CNTOFF 112000
#define IDGOFF (CNTOFF + 40000)   // invdeg f32[200] inside blob
#define ZSOFF  152960             // zsum1[128] | zsum2[128] f32
#define ARENA_SZ2 153984

// prep-kernel grid partition
#define NB_ADJ (2 * NG)                       // 512
#define NB_CX  (2 * NG * 5120 / 256)          // 10240
#define NB_CW  ((2 * (W1SZ + W2SZ)) / 256)    // 704
#define NB_PREP (NB_ADJ + NB_CX + NB_CW)

typedef short short8 __attribute__((ext_vector_type(8)));
typedef float f32x4  __attribute__((ext_vector_type(4)));

__device__ __forceinline__ unsigned short f2bf(float f) {
    union { float f; unsigned int u; } v; v.f = f;
    unsigned int u = v.u;
    u += 0x7FFFu + ((u >> 16) & 1u);       // RNE
    return (unsigned short)(u >> 16);
}

// ---------------------------------------------------------------------------
// Prep: [0,512) adjacency -> RAW u8 counts + fp32 invdeg blob; [512,10752)
// X fp32 -> bf16 slabs (pitch 200, stride 40,960 shorts, pad 0);
// [10752,11456) W convert.
// ---------------------------------------------------------------------------
__global__ __launch_bounds__(256) void prep_kernel(
        const int* __restrict__ sc_ei, const int* __restrict__ fc_ei,
        const float* __restrict__ sc_x, const float* __restrict__ fc_x,
        const float* __restrict__ s1r, const float* __restrict__ s1o,
        const float* __restrict__ f1r, const float* __restrict__ f1o,
        const float* __restrict__ s2r, const float* __restrict__ s2o,
        const float* __restrict__ f2r, const float* __restrict__ f2o,
        unsigned int* __restrict__ C, unsigned short* __restrict__ xb,
        unsigned short* __restrict__ wb) {
    const int b = blockIdx.x, t = threadIdx.x;

    if (b < NB_ADJ) {
        __shared__ unsigned int cnt[10000];    // 200*200 u8 counters in u32
        __shared__ float invdeg[200];
        const int branch = b >> 8, g = b & 255;
        const int* ei = branch ? fc_ei : sc_ei;

        for (int i = t; i < 10000; i += 256) cnt[i] = 0u;
        __syncthreads();
        const int ebase = g * EPG_;
        for (int i = t; i < EPG_; i += 256) {
            int src = ei[ebase + i];
            int dst = ei[E_T + ebase + i];
            int idx = (dst - g * NPG) * NPG + (src - g * NPG);
            atomicAdd(&cnt[idx >> 2], 1u << ((idx & 3) * 8));
        }
        __syncthreads();
        if (t < NPG) {
            unsigned int s = 0;
            for (int w = 0; w < 50; ++w) {
                unsigned int v = cnt[t * 50 + w];
                s += (v & 0xFFu) + ((v >> 8) & 0xFFu) + ((v >> 16) & 0xFFu) + ((v >> 24) & 0xFFu);
            }
            invdeg[t] = 1.0f / fmaxf((float)s, 1.0f);
        }
        __syncthreads();
        // raw blob out: [10000 cnt u32][200 invdeg f32][40 zero u32]
        unsigned int* Cg = C + (size_t)(branch * NG + g) * (CBLOB / 4);
        for (int q = t; q < 10000; q += 256) Cg[q] = cnt[q];
        if (t < 200) ((float*)(Cg + 10000))[t] = invdeg[t];
        if (t < 40) Cg[10200 + t] = 0u;
    } else if (b < NB_ADJ + NB_CX) {
        // ---- X fp32 [node,200] -> bf16 slabs pitch 200, stride 40960, pad zeroed
        int c = (b - NB_ADJ) * 256 + t;          // 0 .. 2*256*5120-1
        int slab = c / 5120;                     // branch*256 + g
        int ci = c - slab * 5120;                // chunk (8 shorts) within slab
        uint4 o;
        if (ci < 5000) {
            int n  = ci / 25;                    // node within graph
            int k8 = ci - n * 25;
            int branch = slab >> 8, g = slab & 255;
            const float* x = branch ? fc_x : sc_x;
            const float* p = x + ((size_t)g * NPG + n) * 200 + k8 * 8;
            float4 a  = *(const float4*)p;
            float4 bb = *(const float4*)(p + 4);
            o.x = (unsigned)f2bf(a.x) | ((unsigned)f2bf(a.y) << 16);
            o.y = (unsigned)f2bf(a.z) | ((unsigned)f2bf(a.w) << 16);
            o.z = (unsigned)f2bf(bb.x) | ((unsigned)f2bf(bb.y) << 16);
            o.w = (unsigned)f2bf(bb.z) | ((unsigned)f2bf(bb.w) << 16);
        } else {
            o.x = o.y = o.z = o.w = 0u;          // slab pad
        }
        *(uint4*)&xb[(size_t)slab * XSTR1 + (size_t)ci * 8] = o;
    } else {
        // ---- weights -> packed W^T bf16 [br0L1|br1L1|br0L2|br1L2], rel|root rows
        int idx = (b - NB_ADJ - NB_CX) * 256 + t;
        float v = 0.0f;
        if (idx < 2 * W1SZ) {
            int branch = idx / W1SZ, rem = idx - branch * W1SZ;
            int c = rem / KP1, k = rem - c * KP1;
            const float* wr = branch ? f1r : s1r;
            const float* wo = branch ? f1o : s1o;
            if (k < 200) v = (c < 128) ? wr[(size_t)k * 128 + c] : wo[(size_t)k * 128 + (c - 128)];
        } else {
            int i2 = idx - 2 * W1SZ;
            int branch = i2 / W2SZ, rem = i2 - branch * W2SZ;
            int c = rem / HDIM, k = rem - c * HDIM;
            const float* wr = branch ? f2r : s2r;
            const float* wo = branch ? f2o : s2o;
            v = (c < 128) ? wr[(size_t)k * 128 + c] : wo[(size_t)k * 128 + (c - 128)];
        }
        wb[idx] = f2bf(v);
    }
}

// ---------------------------------------------------------------------------
// FINAL (= round-16 / best-verified 253.0 µs): fused two-layer kernel,
// A' expanded ONCE in-LDS, AGG loops barrier-free, 9 barriers total.
// Reverted here after rounds 17-19 (EXPAND-delete: net flat; 16-wave
// occupancy: allocator spills 137 MB scratch at 1024 threads, uncontrollable
// from source).  Structure:
//   - stage X slab (80KB) + raw cnt blob (41KB) once per (g,branch) block
//   - phase2-L1 (X x W1 from LDS/global) -> EXPAND_ALL A' bf16 into dead-X
//     region (serves BOTH layers) -> Tt -> AGG1 (pure-LDS, no barriers) ->
//     h in LDS -> phase2-L2 -> Tt2 -> AGG2 -> pool
//   - h never touches HBM; A' never materialized in global bf16
// ---------------------------------------------------------------------------
__global__ __launch_bounds__(512, 1) void fused_kernel(
        const unsigned short* __restrict__ Xb,
        const unsigned short* __restrict__ Wall,
        const unsigned int* __restrict__ Call,
        const float* __restrict__ s1b, const float* __restrict__ f1b,
        const float* __restrict__ s2b, const float* __restrict__ f2b,
        float* __restrict__ z) {
    __shared__ __attribute__((aligned(16))) char arena[ARENA_SZ2];

    const int tid = threadIdx.x;
    const int lane = tid & 63, wid = tid >> 6;   // 8 waves
    const int l15 = lane & 15, quad = lane >> 4;
    const int ms = wid & 1, ns = wid >> 1;       // node half x channel quarter

    const int g = blockIdx.x & 255, branch = blockIdx.x >> 8;

    const unsigned short* Xg = Xb + ((size_t)branch * NG + g) * XSTR1;
    const char* Cg = (const char*)Call + ((size_t)branch * NG + g) * CBLOB;
    const unsigned short* W1 = Wall + (size_t)branch * W1SZ;
    const unsigned short* W2 = Wall + (size_t)2 * W1SZ + (size_t)branch * W2SZ;

    // ---- stage X slab (10 uniform loads), then cnt blob (5 uniform loads)
    {
        __attribute__((address_space(3))) char* lx =
            (__attribute__((address_space(3))) char*)&arena[0];
        for (int j = 0; j <= 9; ++j) {
            int i = (j < 9) ? (j * 512 + tid) : (5000 - 512 + tid);
            const char* gp = (const char*)Xg + (size_t)i * 16;
            __builtin_amdgcn_global_load_lds(
                (const __attribute__((address_space(1))) unsigned int*)gp,
                (__attribute__((address_space(3))) unsigned int*)(lx + (size_t)i * 16),
                16, 0, 0);
        }
        __builtin_amdgcn_sched_barrier(0);
        __attribute__((address_space(3))) char* lc =
            (__attribute__((address_space(3))) char*)&arena[CNTOFF];
        for (int j = 0; j < 5; ++j) {            // 2560 chunks exactly
            int i = j * 512 + tid;
            const char* gp = Cg + (size_t)i * 16;
            __builtin_amdgcn_global_load_lds(
                (const __attribute__((address_space(1))) unsigned int*)gp,
                (__attribute__((address_space(3))) unsigned int*)(lc + (size_t)i * 16),
                16, 0, 0);
        }
    }

    int nrow[7];
#pragma unroll
    for (int mt = 0; mt < 7; ++mt) {
        int s = (ms * 7 + mt) * 16 + l15;
        nrow[mt] = (s > NPG - 1) ? (NPG - 1) : s;   // clamp; killed downstream
    }
    int wrow[2];
#pragma unroll
    for (int nt = 0; nt < 2; ++nt)
        wrow[nt] = (ns * 2 + nt) * 16 + l15;        // ch row 0..127

    // barrier-free agg: acc += Tt x Af, 7 pure-LDS K-steps
    auto AGG = [&](f32x4 (&acc)[2][7]) {
        const short* Tt = (const short*)(arena + TT2OFF);
        const short* Af = (const short*)arena;
#pragma unroll
        for (int ki = 0; ki < 7; ++ki) {
            const int k0 = ki * 32 + quad * 8;
            short8 tf[2];
#pragma unroll
            for (int ct = 0; ct < 2; ++ct)
                tf[ct] = *(const short8*)&Tt[wrow[ct] * TTP + k0];
            short8 afr[7];
#pragma unroll
            for (int dt = 0; dt < 7; ++dt)
                afr[dt] = *(const short8*)&Af[nrow[dt] * AFP + k0];
#pragma unroll
            for (int ct = 0; ct < 2; ++ct)
#pragma unroll
                for (int dt = 0; dt < 7; ++dt)
                    acc[ct][dt] = __builtin_amdgcn_mfma_f32_16x16x32_bf16(
                        tf[ct], afr[dt], acc[ct][dt], 0, 0, 0);
        }
    };

    // T write: acc[m=s][n=c] -> Tt [c 128][s pad 224] at TT2OFF, cols>=200 zero
    auto WRITE_T = [&](f32x4 (&acc)[7][2]) {
        short* Tt = (short*)(arena + TT2OFF);
#pragma unroll
        for (int mt = 0; mt < 7; ++mt) {
            int s0 = (ms * 7 + mt) * 16 + quad * 4;
#pragma unroll
            for (int nt = 0; nt < 2; ++nt) {
                int c = (ns * 2 + nt) * 16 + l15;
                ushort4 o;
                unsigned short* po = (unsigned short*)&o;
#pragma unroll
                for (int r = 0; r < 4; ++r)
                    po[r] = (s0 + r < NPG) ? f2bf(acc[mt][nt][r]) : (unsigned short)0;
                *(ushort4*)&Tt[c * TTP + s0] = o;
            }
        }
    };

    // ================= L1 =================
    {
        f32x4 accT[7][2], accH[2][7];
#pragma unroll
        for (int mt = 0; mt < 7; ++mt)
#pragma unroll
            for (int nt = 0; nt < 2; ++nt)
#pragma unroll
                for (int r = 0; r < 4; ++r) { accT[mt][nt][r] = 0.0f; accH[nt][mt][r] = 0.0f; }

        // F1: X landed (5 cnt loads still in flight)
        asm volatile("s_waitcnt vmcnt(5)\n\ts_barrier" ::: "memory");

        // phase 2: merged transform + root (X from LDS pitch 400B, W1 direct)
#pragma unroll
        for (int ki = 0; ki < 7; ++ki) {
            int cch = ki * 4 + quad;
            if (cch > 24) cch = 24;                 // never read past staged row
            short8 xf[7];
#pragma unroll
            for (int mt = 0; mt < 7; ++mt)
                xf[mt] = *(const short8*)(arena + nrow[mt] * 400 + cch * 16);
            const int kb = ki * 32 + quad * 8;
            short8 wr[2], wo[2];
#pragma unroll
            for (int nt = 0; nt < 2; ++nt) {
                wr[nt] = *(const short8*)&W1[(size_t)wrow[nt] * KP1 + kb];
                wo[nt] = *(const short8*)&W1[(size_t)(128 + wrow[nt]) * KP1 + kb];
            }
#pragma unroll
            for (int mt = 0; mt < 7; ++mt)
#pragma unroll
                for (int nt = 0; nt < 2; ++nt)
                    accT[mt][nt] = __builtin_amdgcn_mfma_f32_16x16x32_bf16(
                        xf[mt], wr[nt], accT[mt][nt], 0, 0, 0);
#pragma unroll
            for (int nt = 0; nt < 2; ++nt)
#pragma unroll
                for (int mt = 0; mt < 7; ++mt)
                    accH[nt][mt] = __builtin_amdgcn_mfma_f32_16x16x32_bf16(
                        wo[nt], xf[mt], accH[nt][mt], 0, 0, 0);
        }

        __syncthreads();   // F2: X dead everywhere; cnt landed (vmcnt drained)

        // EXPAND_ALL: Af[200][AFP], chunks 0..27 (k>=200 zero), over dead X.
        {
            short* Af = (short*)arena;
#pragma unroll
            for (int j = 0; j < 22; ++j) {
                int w = j * 512 + tid;              // 11200 uint2 writes
                if (w < 11200) {
                    int row = w / 56, wj = w - row * 56;   // wj 0..55
                    unsigned int lo = 0u, hi = 0u;
                    if (wj < 50) {                  // k0=wj*4 < 200
                        unsigned int cw = *(const unsigned int*)(arena + CNTOFF + (size_t)(row * 50 + wj) * 4);
                        float inv = *(const float*)(arena + IDGOFF + (size_t)row * 4);
                        unsigned short b0 = f2bf((float)(cw & 0xFFu) * inv);
                        unsigned short b1 = f2bf((float)((cw >> 8) & 0xFFu) * inv);
                        unsigned short b2 = f2bf((float)((cw >> 16) & 0xFFu) * inv);
                        unsigned short b3 = f2bf((float)((cw >> 24) & 0xFFu) * inv);
                        lo = (unsigned)b0 | ((unsigned)b1 << 16);
                        hi = (unsigned)b2 | ((unsigned)b3 << 16);
                    }
                    uint2 o; o.x = lo; o.y = hi;
                    *(uint2*)(Af + row * AFP + wj * 4) = o;
                }
            }
            if (tid < 256) ((float*)(arena + ZSOFF))[tid] = 0.0f;   // zsum1|zsum2
        }
        __syncthreads();   // F3: Af + zsum visible; cnt dead

        WRITE_T(accT);     // Tt over dead cnt region
        __syncthreads();   // F4: Tt visible

        AGG(accH);         // barrier-free
        __syncthreads();   // F5: all waves done reading Tt (h will overwrite)

        // epilogue: relu+bias, pool -> zsum1, h -> LDS at TT2OFF pitch 136
        const float* brel = branch ? f1b : s1b;
        float* zs1 = (float*)(arena + ZSOFF);
        short* hb = (short*)(arena + TT2OFF);
#pragma unroll
        for (int ct = 0; ct < 2; ++ct) {
            const int c0 = (ns * 2 + ct) * 16 + quad * 4;
            float bb[4], part[4];
#pragma unroll
            for (int r = 0; r < 4; ++r) { bb[r] = brel[c0 + r]; part[r] = 0.0f; }
#pragma unroll
            for (int dt = 0; dt < 7; ++dt) {
                const int d = (ms * 7 + dt) * 16 + l15;
                if (d < NPG) {
                    ushort4 o;
                    unsigned short* po = (unsigned short*)&o;
#pragma unroll
                    for (int r = 0; r < 4; ++r) {
                        float v = fmaxf(accH[ct][dt][r] + bb[r], 0.0f);
                        part[r] += v;
                        po[r] = f2bf(v);
                    }
                    *(ushort4*)&hb[d * HP + c0] = o;
                }
            }
#pragma unroll
            for (int r = 0; r < 4; ++r) {
                float v = part[r];
                v += __shfl_xor(v, 1);
                v += __shfl_xor(v, 2);
                v += __shfl_xor(v, 4);
                v += __shfl_xor(v, 8);
                if (l15 == 0) atomicAdd(&zs1[c0 + r], v);
            }
        }
        __syncthreads();   // F6: h + zsum1 final
        if (tid < 128)
            z[(size_t)g * 512 + branch * 256 + 0 + tid] =
                zs1[tid] * (branch ? 1.0f : (1.0f / 200.0f));
    }

    // ================= L2 =================
    {
        f32x4 accT[7][2], accH[2][7];
#pragma unroll
        for (int mt = 0; mt < 7; ++mt)
#pragma unroll
            for (int nt = 0; nt < 2; ++nt)
#pragma unroll
                for (int r = 0; r < 4; ++r) { accT[mt][nt][r] = 0.0f; accH[nt][mt][r] = 0.0f; }

        // phase 2: h (LDS pitch 272B, chunks 0..15 all real) x W2 (direct)
#pragma unroll
        for (int ki = 0; ki < 4; ++ki) {
            short8 xf[7];
#pragma unroll
            for (int mt = 0; mt < 7; ++mt)
                xf[mt] = *(const short8*)(arena + TT2OFF + nrow[mt] * (HP * 2) + (ki * 4 + quad) * 16);
            const int kb = ki * 32 + quad * 8;
            short8 wr[2], wo[2];
#pragma unroll
            for (int nt = 0; nt < 2; ++nt) {
                wr[nt] = *(const short8*)&W2[(size_t)wrow[nt] * HDIM + kb];
                wo[nt] = *(const short8*)&W2[(size_t)(128 + wrow[nt]) * HDIM + kb];
            }
#pragma unroll
            for (int mt = 0; mt < 7; ++mt)
#pragma unroll
                for (int nt = 0; nt < 2; ++nt)
                    accT[mt][nt] = __builtin_amdgcn_mfma_f32_16x16x32_bf16(
                        xf[mt], wr[nt], accT[mt][nt], 0, 0, 0);
#pragma unroll
            for (int nt = 0; nt < 2; ++nt)
#pragma unroll
                for (int mt = 0; mt < 7; ++mt)
                    accH[nt][mt] = __builtin_amdgcn_mfma_f32_16x16x32_bf16(
                        wo[nt], xf[mt], accH[nt][mt], 0, 0, 0);
        }

        __syncthreads();   // F7: h dead
        WRITE_T(accT);     // Tt2 overwrites h region
        __syncthreads();   // F8: Tt2 visible

        AGG(accH);         // barrier-free; Af still valid

        // epilogue: pool only -> zsum2 (separate region; no Tt-write hazard)
        const float* brel = branch ? f2b : s2b;
        float* zs2 = (float*)(arena + ZSOFF + 512);
#pragma unroll
        for (int ct = 0; ct < 2; ++ct) {
            const int c0 = (ns * 2 + ct) * 16 + quad * 4;
            float bb[4], part[4];
#pragma unroll
            for (int r = 0; r < 4; ++r) { bb[r] = brel[c0 + r]; part[r] = 0.0f; }
#pragma unroll
            for (int dt = 0; dt < 7; ++dt) {
                const int d = (ms * 7 + dt) * 16 + l15;
                if (d < NPG) {
#pragma unroll
                    for (int r = 0; r < 4; ++r)
                        part[r] += fmaxf(accH[ct][dt][r] + bb[r], 0.0f);
                }
            }
#pragma unroll
            for (int r = 0; r < 4; ++r) {
                float v = part[r];
                v += __shfl_xor(v, 1);
                v += __shfl_xor(v, 2);
                v += __shfl_xor(v, 4);
                v += __shfl_xor(v, 8);
                if (l15 == 0) atomicAdd(&zs2[c0 + r], v);
            }
        }
        __syncthreads();   // F9: zsum2 complete
        if (tid < 128)
            z[(size_t)g * 512 + branch * 256 + 128 + tid] =
                zs2[tid] * (branch ? 1.0f : (1.0f / 200.0f));
    }
}

// ---------------------------------------------------------------------------
// MLP head (fp32): z[512] -> relu(lin1)[128] -> relu(lin2)[64] -> lin3[2]
// -> log_softmax. One block per graph.  (unchanged)
// ---------------------------------------------------------------------------
__global__ __launch_bounds__(128) void mlp_kernel(const float* __restrict__ z,
                                                  const float* __restrict__ w1, const float* __restrict__ b1,
                                                  const float* __restrict__ w2, const float* __restrict__ b2,
                                                  const float* __restrict__ w3, const float* __restrict__ b3,
                                                  float* __restrict__ out) {
    __shared__ float zs[512];
    __shared__ float l1[128];
    __shared__ float l2[64];
    __shared__ float logits[2];
    int g = blockIdx.x, t = threadIdx.x;

#pragma unroll
    for (int i = 0; i < 4; ++i) zs[t + 128 * i] = z[(size_t)g * 512 + t + 128 * i];
    __syncthreads();

    float s = b1[t];
#pragma unroll 8
    for (int k = 0; k < 512; ++k) s = fmaf(zs[k], w1[k * 128 + t], s);
    l1[t] = fmaxf(s, 0.0f);
    __syncthreads();

    if (t < 64) {
        float s2 = b2[t];
#pragma unroll 8
        for (int k = 0; k < 128; ++k) s2 = fmaf(l1[k], w2[k * 64 + t], s2);
        l2[t] = fmaxf(s2, 0.0f);
    }
    __syncthreads();

    if (t < 2) {
        float s3 = b3[t];
        for (int k = 0; k < 64; ++k) s3 = fmaf(l2[k], w3[k * 2 + t], s3);
        logits[t] = s3;
    }
    __syncthreads();

    if (t < 2) {
        float m = fmaxf(logits[0], logits[1]);
        float lse = m + logf(expf(logits[0] - m) + expf(logits[1] - m));
        out[(size_t)g * 2 + t] = logits[t] - lse;
    }
}

// ---------------------------------------------------------------------------
extern "C" void kernel_launch(void* const* d_in, const int* in_sizes, int n_in,
                              void* d_out, int out_size, void* d_ws, size_t ws_size,
                              hipStream_t stream) {
    const float* sc_x = (const float*)d_in[0];
    const float* fc_x = (const float*)d_in[1];
    const int* sc_ei  = (const int*)d_in[2];
    const int* fc_ei  = (const int*)d_in[3];
    const float* sc1_wrel = (const float*)d_in[5];
    const float* sc1_brel = (const float*)d_in[6];
    const float* sc1_wroot = (const float*)d_in[7];
    const float* sc2_wrel = (const float*)d_in[8];
    const float* sc2_brel = (const float*)d_in[9];
    const float* sc2_wroot = (const float*)d_in[10];
    const float* fc1_wrel = (const float*)d_in[11];
    const float* fc1_brel = (const float*)d_in[12];
    const float* fc1_wroot = (const float*)d_in[13];
    const float* fc2_wrel = (const float*)d_in[14];
    const float* fc2_brel = (const float*)d_in[15];
    const float* fc2_wroot = (const float*)d_in[16];
    const float* lin1_w = (const float*)d_in[17];
    const float* lin1_b = (const float*)d_in[18];
    const float* lin2_w = (const float*)d_in[19];
    const float* lin2_b = (const float*)d_in[20];
    const float* lin3_w = (const float*)d_in[21];
    const float* lin3_b = (const float*)d_in[22];

    // Workspace: Xb (bf16 slabs) | Cb (cnt blobs) | Wb | z   (~64 MB)
    unsigned short* Xb = (unsigned short*)d_ws;                  // 2*256*40960 shorts
    unsigned int*  Cb = (unsigned int*)(Xb + (size_t)2 * NG * XSTR1);  // 2*256*10240 u32
    unsigned short* Wb = (unsigned short*)(Cb + (size_t)2 * NG * (CBLOB / 4));
    float* z = (float*)(Wb + (size_t)2 * (W1SZ + W2SZ));         // 256*512 fp32

    prep_kernel<<<NB_PREP, 256, 0, stream>>>(
        sc_ei, fc_ei, sc_x, fc_x,
        sc1_wrel, sc1_wroot, fc1_wrel, fc1_wroot,
        sc2_wrel, sc2_wroot, fc2_wrel, fc2_wroot,
        Cb, Xb, Wb);

    fused_kernel<<<512, 512, 0, stream>>>(
        Xb, Wb, Cb, sc1_brel, fc1_brel, sc2_brel, fc2_brel, z);

    mlp_kernel<<<NG, 128, 0, stream>>>(z, lin1_w, lin1_b, lin2_w, lin2_b,
                                       lin3_w, lin3_b, (float*)d_out);
}

// Round 14
// 241.881 us; speedup vs baseline: 1.1924x; 1.0625x over previous
//
#include <hip/hip_runtime.h>
#include <math.h>

#define NPG   200                 // nodes per graph
#define HDIM  128
#define NG    256
#define NT_T  (NG * NPG)          // 51200
#define EPG_  3200
#define E_T   (NG * EPG_)         // 819200
#define KP1   224                 // layer-1 K (200) padded to mult of 32 (W pitch)
#define TTP   232                 // Tt LDS pitch (shorts): 29 chunks (mod8=5, spread)
#define AFP   232                 // A'full LDS pitch (shorts): same spread
#define HP    136                 // h LDS pitch (shorts): 17 chunks (mod8=1, spread)
#define W1SZ  (256 * KP1)
#define W2SZ  (256 * HDIM)

// LDS arena (bytes):
//   Af [0,92800) over dead X | Tt/h [92800,152192) over dead cnt+invdeg |
//   cnt u32[10000] [112000,152000) | invdeg f32[200] [152000,152800) |
//   zsum [152960,153984)
#define TT2OFF 92800
#define CNTOFF 112000
#define IDGOFF 152000
#define ZSOFF  152960             // zsum1[128] | zsum2[128] f32
#define ARENA_SZ2 153984

#define NB_CW  ((2 * (W1SZ + W2SZ)) / 256)    // 704

typedef short short8 __attribute__((ext_vector_type(8)));
typedef float f32x4  __attribute__((ext_vector_type(4)));

__device__ __forceinline__ unsigned short f2bf(float f) {
    union { float f; unsigned int u; } v; v.f = f;
    unsigned int u = v.u;
    u += 0x7FFFu + ((u >> 16) & 1u);       // RNE
    return (unsigned short)(u >> 16);
}

// ---------------------------------------------------------------------------
// Round-20 prep: W convert ONLY (X convert and adjacency moved into the
// fused kernel, which reads the original fp32/edge inputs directly --
// deletes ~126 MB of HBM round-trips and a serial kernel stage).
// Packing identical to all prior rounds: [br0L1|br1L1|br0L2|br1L2], rel|root.
// ---------------------------------------------------------------------------
__global__ __launch_bounds__(256) void prep_w_kernel(
        const float* __restrict__ s1r, const float* __restrict__ s1o,
        const float* __restrict__ f1r, const float* __restrict__ f1o,
        const float* __restrict__ s2r, const float* __restrict__ s2o,
        const float* __restrict__ f2r, const float* __restrict__ f2o,
        unsigned short* __restrict__ wb) {
    int idx = blockIdx.x * 256 + threadIdx.x;
    float v = 0.0f;
    if (idx < 2 * W1SZ) {
        int branch = idx / W1SZ, rem = idx - branch * W1SZ;
        int c = rem / KP1, k = rem - c * KP1;
        const float* wr = branch ? f1r : s1r;
        const float* wo = branch ? f1o : s1o;
        if (k < 200) v = (c < 128) ? wr[(size_t)k * 128 + c] : wo[(size_t)k * 128 + (c - 128)];
    } else {
        int i2 = idx - 2 * W1SZ;
        int branch = i2 / W2SZ, rem = i2 - branch * W2SZ;
        int c = rem / HDIM, k = rem - c * HDIM;
        const float* wr = branch ? f2r : s2r;
        const float* wo = branch ? f2o : s2o;
        v = (c < 128) ? wr[(size_t)k * 128 + c] : wo[(size_t)k * 128 + (c - 128)];
    }
    wb[idx] = f2bf(v);
}

// ---------------------------------------------------------------------------
// Round-20 fused kernel: self-contained per (g,branch) block.
// Front-end (new): zero cnt -> [edge LDS-atomics || X fp32->bf16 reg-stage]
// -> invdeg -> phase2-L1.  Everything from phase2 on is VERBATIM round-13
// (best-verified): EXPAND Af once over dead X, barrier-free AGGs, h in LDS,
// 9 downstream barriers.  Bitwise-identical output (same f2bf bits, same
// MFMA order/operands).
// ---------------------------------------------------------------------------
__global__ __launch_bounds__(512, 1) void fused_kernel(
        const float* __restrict__ sc_x, const float* __restrict__ fc_x,
        const int* __restrict__ sc_ei, const int* __restrict__ fc_ei,
        const unsigned short* __restrict__ Wall,
        const float* __restrict__ s1b, const float* __restrict__ f1b,
        const float* __restrict__ s2b, const float* __restrict__ f2b,
        float* __restrict__ z) {
    __shared__ __attribute__((aligned(16))) char arena[ARENA_SZ2];

    const int tid = threadIdx.x;
    const int lane = tid & 63, wid = tid >> 6;   // 8 waves
    const int l15 = lane & 15, quad = lane >> 4;
    const int ms = wid & 1, ns = wid >> 1;       // node half x channel quarter

    const int g = blockIdx.x & 255, branch = blockIdx.x >> 8;

    const float* Xsrc = (branch ? fc_x : sc_x) + (size_t)g * NPG * 200;  // 160,000 B
    const int*   ei   = branch ? fc_ei : sc_ei;
    const unsigned short* W1 = Wall + (size_t)branch * W1SZ;
    const unsigned short* W2 = Wall + (size_t)2 * W1SZ + (size_t)branch * W2SZ;

    unsigned int* cnt = (unsigned int*)(arena + CNTOFF);
    float* invdeg = (float*)(arena + IDGOFF);

    // ---- front-end step 1: zero cnt[10000]
    for (int q = tid; q < 10000; q += 512) cnt[q] = 0u;
    __syncthreads();

    // ---- step 2: edge atomics (issue first; long-latency LDS atomics fly
    // while the X stage loads stream) + X fp32 -> bf16 staging into [0,80000)
    {
        const int ebase = g * EPG_;
        for (int i = tid; i < EPG_; i += 512) {
            int src = ei[ebase + i];
            int dst = ei[E_T + ebase + i];
            int idx = (dst - g * NPG) * NPG + (src - g * NPG);
            atomicAdd(&cnt[idx >> 2], 1u << ((idx & 3) * 8));
        }
        // X: 10,000 fp32 dwordx4 chunks -> 8B bf16 each, linear layout
        short* xb = (short*)arena;
#pragma unroll
        for (int j = 0; j < 20; ++j) {
            int i = j * 512 + tid;
            if (i < 10000) {
                float4 a = *(const float4*)(Xsrc + (size_t)i * 4);
                unsigned int lo = (unsigned)f2bf(a.x) | ((unsigned)f2bf(a.y) << 16);
                unsigned int hi = (unsigned)f2bf(a.z) | ((unsigned)f2bf(a.w) << 16);
                uint2 o; o.x = lo; o.y = hi;
                *(uint2*)(xb + (size_t)i * 4) = o;
            }
        }
    }
    __syncthreads();

    // ---- step 3: invdeg[200]
    if (tid < NPG) {
        unsigned int s = 0;
        for (int w = 0; w < 50; ++w) {
            unsigned int v = cnt[tid * 50 + w];
            s += (v & 0xFFu) + ((v >> 8) & 0xFFu) + ((v >> 16) & 0xFFu) + ((v >> 24) & 0xFFu);
        }
        invdeg[tid] = 1.0f / fmaxf((float)s, 1.0f);
    }
    __syncthreads();

    int nrow[7];
#pragma unroll
    for (int mt = 0; mt < 7; ++mt) {
        int s = (ms * 7 + mt) * 16 + l15;
        nrow[mt] = (s > NPG - 1) ? (NPG - 1) : s;   // clamp; killed downstream
    }
    int wrow[2];
#pragma unroll
    for (int nt = 0; nt < 2; ++nt)
        wrow[nt] = (ns * 2 + nt) * 16 + l15;        // ch row 0..127

    // barrier-free agg: acc += Tt x Af, 7 pure-LDS K-steps  (verbatim r13)
    auto AGG = [&](f32x4 (&acc)[2][7]) {
        const short* Tt = (const short*)(arena + TT2OFF);
        const short* Af = (const short*)arena;
#pragma unroll
        for (int ki = 0; ki < 7; ++ki) {
            const int k0 = ki * 32 + quad * 8;
            short8 tf[2];
#pragma unroll
            for (int ct = 0; ct < 2; ++ct)
                tf[ct] = *(const short8*)&Tt[wrow[ct] * TTP + k0];
            short8 afr[7];
#pragma unroll
            for (int dt = 0; dt < 7; ++dt)
                afr[dt] = *(const short8*)&Af[nrow[dt] * AFP + k0];
#pragma unroll
            for (int ct = 0; ct < 2; ++ct)
#pragma unroll
                for (int dt = 0; dt < 7; ++dt)
                    acc[ct][dt] = __builtin_amdgcn_mfma_f32_16x16x32_bf16(
                        tf[ct], afr[dt], acc[ct][dt], 0, 0, 0);
        }
    };

    // T write: acc[m=s][n=c] -> Tt [c 128][s pad 224] at TT2OFF, cols>=200 zero
    auto WRITE_T = [&](f32x4 (&acc)[7][2]) {
        short* Tt = (short*)(arena + TT2OFF);
#pragma unroll
        for (int mt = 0; mt < 7; ++mt) {
            int s0 = (ms * 7 + mt) * 16 + quad * 4;
#pragma unroll
            for (int nt = 0; nt < 2; ++nt) {
                int c = (ns * 2 + nt) * 16 + l15;
                ushort4 o;
                unsigned short* po = (unsigned short*)&o;
#pragma unroll
                for (int r = 0; r < 4; ++r)
                    po[r] = (s0 + r < NPG) ? f2bf(acc[mt][nt][r]) : (unsigned short)0;
                *(ushort4*)&Tt[c * TTP + s0] = o;
            }
        }
    };

    // ================= L1 =================
    {
        f32x4 accT[7][2], accH[2][7];
#pragma unroll
        for (int mt = 0; mt < 7; ++mt)
#pragma unroll
            for (int nt = 0; nt < 2; ++nt)
#pragma unroll
                for (int r = 0; r < 4; ++r) { accT[mt][nt][r] = 0.0f; accH[nt][mt][r] = 0.0f; }

        // phase 2: merged transform + root (X from LDS pitch 400B, W1 direct)
#pragma unroll
        for (int ki = 0; ki < 7; ++ki) {
            int cch = ki * 4 + quad;
            if (cch > 24) cch = 24;                 // never read past staged row
            short8 xf[7];
#pragma unroll
            for (int mt = 0; mt < 7; ++mt)
                xf[mt] = *(const short8*)(arena + nrow[mt] * 400 + cch * 16);
            const int kb = ki * 32 + quad * 8;
            short8 wr[2], wo[2];
#pragma unroll
            for (int nt = 0; nt < 2; ++nt) {
                wr[nt] = *(const short8*)&W1[(size_t)wrow[nt] * KP1 + kb];
                wo[nt] = *(const short8*)&W1[(size_t)(128 + wrow[nt]) * KP1 + kb];
            }
#pragma unroll
            for (int mt = 0; mt < 7; ++mt)
#pragma unroll
                for (int nt = 0; nt < 2; ++nt)
                    accT[mt][nt] = __builtin_amdgcn_mfma_f32_16x16x32_bf16(
                        xf[mt], wr[nt], accT[mt][nt], 0, 0, 0);
#pragma unroll
            for (int nt = 0; nt < 2; ++nt)
#pragma unroll
                for (int mt = 0; mt < 7; ++mt)
                    accH[nt][mt] = __builtin_amdgcn_mfma_f32_16x16x32_bf16(
                        wo[nt], xf[mt], accH[nt][mt], 0, 0, 0);
        }

        __syncthreads();   // F2: X dead everywhere; cnt+invdeg complete

        // EXPAND_ALL: Af[200][AFP], chunks 0..27 (k>=200 zero), over dead X.
        {
            short* Af = (short*)arena;
#pragma unroll
            for (int j = 0; j < 22; ++j) {
                int w = j * 512 + tid;              // 11200 uint2 writes
                if (w < 11200) {
                    int row = w / 56, wj = w - row * 56;   // wj 0..55
                    unsigned int lo = 0u, hi = 0u;
                    if (wj < 50) {                  // k0=wj*4 < 200
                        unsigned int cw = cnt[row * 50 + wj];
                        float inv = invdeg[row];
                        unsigned short b0 = f2bf((float)(cw & 0xFFu) * inv);
                        unsigned short b1 = f2bf((float)((cw >> 8) & 0xFFu) * inv);
                        unsigned short b2 = f2bf((float)((cw >> 16) & 0xFFu) * inv);
                        unsigned short b3 = f2bf((float)((cw >> 24) & 0xFFu) * inv);
                        lo = (unsigned)b0 | ((unsigned)b1 << 16);
                        hi = (unsigned)b2 | ((unsigned)b3 << 16);
                    }
                    uint2 o; o.x = lo; o.y = hi;
                    *(uint2*)(Af + row * AFP + wj * 4) = o;
                }
            }
            if (tid < 256) ((float*)(arena + ZSOFF))[tid] = 0.0f;   // zsum1|zsum2
        }
        __syncthreads();   // F3: Af + zsum visible; cnt+invdeg dead

        WRITE_T(accT);     // Tt over dead cnt region
        __syncthreads();   // F4: Tt visible

        AGG(accH);         // barrier-free
        __syncthreads();   // F5: all waves done reading Tt (h will overwrite)

        // epilogue: relu+bias, pool -> zsum1, h -> LDS at TT2OFF pitch 136
        const float* brel = branch ? f1b : s1b;
        float* zs1 = (float*)(arena + ZSOFF);
        short* hb = (short*)(arena + TT2OFF);
#pragma unroll
        for (int ct = 0; ct < 2; ++ct) {
            const int c0 = (ns * 2 + ct) * 16 + quad * 4;
            float bb[4], part[4];
#pragma unroll
            for (int r = 0; r < 4; ++r) { bb[r] = brel[c0 + r]; part[r] = 0.0f; }
#pragma unroll
            for (int dt = 0; dt < 7; ++dt) {
                const int d = (ms * 7 + dt) * 16 + l15;
                if (d < NPG) {
                    ushort4 o;
                    unsigned short* po = (unsigned short*)&o;
#pragma unroll
                    for (int r = 0; r < 4; ++r) {
                        float v = fmaxf(accH[ct][dt][r] + bb[r], 0.0f);
                        part[r] += v;
                        po[r] = f2bf(v);
                    }
                    *(ushort4*)&hb[d * HP + c0] = o;
                }
            }
#pragma unroll
            for (int r = 0; r < 4; ++r) {
                float v = part[r];
                v += __shfl_xor(v, 1);
                v += __shfl_xor(v, 2);
                v += __shfl_xor(v, 4);
                v += __shfl_xor(v, 8);
                if (l15 == 0) atomicAdd(&zs1[c0 + r], v);
            }
        }
        __syncthreads();   // F6: h + zsum1 final
        if (tid < 128)
            z[(size_t)g * 512 + branch * 256 + 0 + tid] =
                zs1[tid] * (branch ? 1.0f : (1.0f / 200.0f));
    }

    // ================= L2 =================
    {
        f32x4 accT[7][2], accH[2][7];
#pragma unroll
        for (int mt = 0; mt < 7; ++mt)
#pragma unroll
            for (int nt = 0; nt < 2; ++nt)
#pragma unroll
                for (int r = 0; r < 4; ++r) { accT[mt][nt][r] = 0.0f; accH[nt][mt][r] = 0.0f; }

        // phase 2: h (LDS pitch 272B, chunks 0..15 all real) x W2 (direct)
#pragma unroll
        for (int ki = 0; ki < 4; ++ki) {
            short8 xf[7];
#pragma unroll
            for (int mt = 0; mt < 7; ++mt)
                xf[mt] = *(const short8*)(arena + TT2OFF + nrow[mt] * (HP * 2) + (ki * 4 + quad) * 16);
            const int kb = ki * 32 + quad * 8;
            short8 wr[2], wo[2];
#pragma unroll
            for (int nt = 0; nt < 2; ++nt) {
                wr[nt] = *(const short8*)&W2[(size_t)wrow[nt] * HDIM + kb];
                wo[nt] = *(const short8*)&W2[(size_t)(128 + wrow[nt]) * HDIM + kb];
            }
#pragma unroll
            for (int mt = 0; mt < 7; ++mt)
#pragma unroll
                for (int nt = 0; nt < 2; ++nt)
                    accT[mt][nt] = __builtin_amdgcn_mfma_f32_16x16x32_bf16(
                        xf[mt], wr[nt], accT[mt][nt], 0, 0, 0);
#pragma unroll
            for (int nt = 0; nt < 2; ++nt)
#pragma unroll
                for (int mt = 0; mt < 7; ++mt)
                    accH[nt][mt] = __builtin_amdgcn_mfma_f32_16x16x32_bf16(
                        wo[nt], xf[mt], accH[nt][mt], 0, 0, 0);
        }

        __syncthreads();   // F7: h dead
        WRITE_T(accT);     // Tt2 overwrites h region
        __syncthreads();   // F8: Tt2 visible

        AGG(accH);         // barrier-free; Af still valid

        // epilogue: pool only -> zsum2 (separate region; no Tt-write hazard)
        const float* brel = branch ? f2b : s2b;
        float* zs2 = (float*)(arena + ZSOFF + 512);
#pragma unroll
        for (int ct = 0; ct < 2; ++ct) {
            const int c0 = (ns * 2 + ct) * 16 + quad * 4;
            float bb[4], part[4];
#pragma unroll
            for (int r = 0; r < 4; ++r) { bb[r] = brel[c0 + r]; part[r] = 0.0f; }
#pragma unroll
            for (int dt = 0; dt < 7; ++dt) {
                const int d = (ms * 7 + dt) * 16 + l15;
                if (d < NPG) {
#pragma unroll
                    for (int r = 0; r < 4; ++r)
                        part[r] += fmaxf(accH[ct][dt][r] + bb[r], 0.0f);
                }
            }
#pragma unroll
            for (int r = 0; r < 4; ++r) {
                float v = part[r];
                v += __shfl_xor(v, 1);
                v += __shfl_xor(v, 2);
                v += __shfl_xor(v, 4);
                v += __shfl_xor(v, 8);
                if (l15 == 0) atomicAdd(&zs2[c0 + r], v);
            }
        }
        __syncthreads();   // F9: zsum2 complete
        if (tid < 128)
            z[(size_t)g * 512 + branch * 256 + 128 + tid] =
                zs2[tid] * (branch ? 1.0f : (1.0f / 200.0f));
    }
}

// ---------------------------------------------------------------------------
// MLP head (fp32): z[512] -> relu(lin1)[128] -> relu(lin2)[64] -> lin3[2]
// -> log_softmax. One block per graph.  (unchanged)
// ---------------------------------------------------------------------------
__global__ __launch_bounds__(128) void mlp_kernel(const float* __restrict__ z,
                                                  const float* __restrict__ w1, const float* __restrict__ b1,
                                                  const float* __restrict__ w2, const float* __restrict__ b2,
                                                  const float* __restrict__ w3, const float* __restrict__ b3,
                                                  float* __restrict__ out) {
    __shared__ float zs[512];
    __shared__ float l1[128];
    __shared__ float l2[64];
    __shared__ float logits[2];
    int g = blockIdx.x, t = threadIdx.x;

#pragma unroll
    for (int i = 0; i < 4; ++i) zs[t + 128 * i] = z[(size_t)g * 512 + t + 128 * i];
    __syncthreads();

    float s = b1[t];
#pragma unroll 8
    for (int k = 0; k < 512; ++k) s = fmaf(zs[k], w1[k * 128 + t], s);
    l1[t] = fmaxf(s, 0.0f);
    __syncthreads();

    if (t < 64) {
        float s2 = b2[t];
#pragma unroll 8
        for (int k = 0; k < 128; ++k) s2 = fmaf(l1[k], w2[k * 64 + t], s2);
        l2[t] = fmaxf(s2, 0.0f);
    }
    __syncthreads();

    if (t < 2) {
        float s3 = b3[t];
        for (int k = 0; k < 64; ++k) s3 = fmaf(l2[k], w3[k * 2 + t], s3);
        logits[t] = s3;
    }
    __syncthreads();

    if (t < 2) {
        float m = fmaxf(logits[0], logits[1]);
        float lse = m + logf(expf(logits[0] - m) + expf(logits[1] - m));
        out[(size_t)g * 2 + t] = logits[t] - lse;
    }
}

// ---------------------------------------------------------------------------
extern "C" void kernel_launch(void* const* d_in, const int* in_sizes, int n_in,
                              void* d_out, int out_size, void* d_ws, size_t ws_size,
                              hipStream_t stream) {
    const float* sc_x = (const float*)d_in[0];
    const float* fc_x = (const float*)d_in[1];
    const int* sc_ei  = (const int*)d_in[2];
    const int* fc_ei  = (const int*)d_in[3];
    const float* sc1_wrel = (const float*)d_in[5];
    const float* sc1_brel = (const float*)d_in[6];
    const float* sc1_wroot = (const float*)d_in[7];
    const float* sc2_wrel = (const float*)d_in[8];
    const float* sc2_brel = (const float*)d_in[9];
    const float* sc2_wroot = (const float*)d_in[10];
    const float* fc1_wrel = (const float*)d_in[11];
    const float* fc1_brel = (const float*)d_in[12];
    const float* fc1_wroot = (const float*)d_in[13];
    const float* fc2_wrel = (const float*)d_in[14];
    const float* fc2_brel = (const float*)d_in[15];
    const float* fc2_wroot = (const float*)d_in[16];
    const float* lin1_w = (const float*)d_in[17];
    const float* lin1_b = (const float*)d_in[18];
    const float* lin2_w = (const float*)d_in[19];
    const float* lin2_b = (const float*)d_in[20];
    const float* lin3_w = (const float*)d_in[21];
    const float* lin3_b = (const float*)d_in[22];

    // Workspace: Wb (packed bf16 weights) | z   (<1 MB)
    unsigned short* Wb = (unsigned short*)d_ws;                  // 2*(W1SZ+W2SZ)
    float* z = (float*)(Wb + (size_t)2 * (W1SZ + W2SZ));         // 256*512 fp32

    prep_w_kernel<<<NB_CW, 256, 0, stream>>>(
        sc1_wrel, sc1_wroot, fc1_wrel, fc1_wroot,
        sc2_wrel, sc2_wroot, fc2_wrel, fc2_wroot, Wb);

    fused_kernel<<<512, 512, 0, stream>>>(
        sc_x, fc_x, sc_ei, fc_ei, Wb,
        sc1_brel, fc1_brel, sc2_brel, fc2_brel, z);

    mlp_kernel<<<NG, 128, 0, stream>>>(z, lin1_w, lin1_b, lin2_w, lin2_b,
                                       lin3_w, lin3_b, (float*)d_out);
}

// Round 15
// 236.393 us; speedup vs baseline: 1.2201x; 1.0232x over previous
//
#include <hip/hip_runtime.h>
#include <hip/hip_bf16.h>
#include <math.h>

#define NPG   200                 // nodes per graph
#define HDIM  128
#define NG    256
#define NT_T  (NG * NPG)          // 51200
#define EPG_  3200
#define E_T   (NG * EPG_)         // 819200
#define KP1   224                 // layer-1 K (200) padded to mult of 32 (W pitch)
#define TTP   232                 // Tt LDS pitch (shorts): 29 chunks (mod8=5, spread)
#define AFP   232                 // A'full LDS pitch (shorts): same spread
#define HP    136                 // h LDS pitch (shorts): 17 chunks (mod8=1, spread)
#define W1SZ  (256 * KP1)
#define W2SZ  (256 * HDIM)

// LDS arena (bytes):
//   Af [0,92800) over dead X | Tt/h [92800,152192) over dead cnt+invdeg |
//   cnt u32[10000] [112000,152000) | invdeg f32[200] [152000,152800) |
//   zsum [152960,153984)
#define TT2OFF 92800
#define CNTOFF 112000
#define IDGOFF 152000
#define ZSOFF  152960             // zsum1[128] | zsum2[128] f32
#define ARENA_SZ2 153984

#define NB_CW  ((2 * (W1SZ + W2SZ)) / 256)    // 704

typedef short short8 __attribute__((ext_vector_type(8)));
typedef float f32x4  __attribute__((ext_vector_type(4)));

// Round-21: HW bf16 conversion (v_cvt_pk_bf16_f32 path, RNE — bit-identical
// to the old add-round-shift trick for finite values, ~4x fewer VALU ops).
// Evidence (r14): VALUBusy 24.2% with ~1200-1500 manual-conversion VALU ops
// per thread across X-convert/EXPAND/WRITE_T/h paths.
__device__ __forceinline__ unsigned short f2bf(float f) {
    union { __hip_bfloat16 b; unsigned short u; } v;
    v.b = __float2bfloat16(f);
    return v.u;
}

// ---------------------------------------------------------------------------
// Prep: W convert ONLY (X convert and adjacency live in the fused kernel).
// Packing identical to all prior rounds: [br0L1|br1L1|br0L2|br1L2], rel|root.
// ---------------------------------------------------------------------------
__global__ __launch_bounds__(256) void prep_w_kernel(
        const float* __restrict__ s1r, const float* __restrict__ s1o,
        const float* __restrict__ f1r, const float* __restrict__ f1o,
        const float* __restrict__ s2r, const float* __restrict__ s2o,
        const float* __restrict__ f2r, const float* __restrict__ f2o,
        unsigned short* __restrict__ wb) {
    int idx = blockIdx.x * 256 + threadIdx.x;
    float v = 0.0f;
    if (idx < 2 * W1SZ) {
        int branch = idx / W1SZ, rem = idx - branch * W1SZ;
        int c = rem / KP1, k = rem - c * KP1;
        const float* wr = branch ? f1r : s1r;
        const float* wo = branch ? f1o : s1o;
        if (k < 200) v = (c < 128) ? wr[(size_t)k * 128 + c] : wo[(size_t)k * 128 + (c - 128)];
    } else {
        int i2 = idx - 2 * W1SZ;
        int branch = i2 / W2SZ, rem = i2 - branch * W2SZ;
        int c = rem / HDIM, k = rem - c * HDIM;
        const float* wr = branch ? f2r : s2r;
        const float* wo = branch ? f2o : s2o;
        v = (c < 128) ? wr[(size_t)k * 128 + c] : wo[(size_t)k * 128 + (c - 128)];
    }
    wb[idx] = f2bf(v);
}

// ---------------------------------------------------------------------------
// Fused kernel (structure = round-14, best-verified 241.9 µs): self-contained
// per (g,branch) block.  Front-end: zero cnt -> [edge LDS-atomics || X fp32
// ->bf16 reg-stage] -> invdeg.  Then the verbatim r13 pipeline: phase2-L1,
// EXPAND Af once over dead X, barrier-free AGGs, h in LDS, 9 barriers.
// Only change this round: f2bf uses the HW conversion (see above).
// ---------------------------------------------------------------------------
__global__ __launch_bounds__(512, 1) void fused_kernel(
        const float* __restrict__ sc_x, const float* __restrict__ fc_x,
        const int* __restrict__ sc_ei, const int* __restrict__ fc_ei,
        const unsigned short* __restrict__ Wall,
        const float* __restrict__ s1b, const float* __restrict__ f1b,
        const float* __restrict__ s2b, const float* __restrict__ f2b,
        float* __restrict__ z) {
    __shared__ __attribute__((aligned(16))) char arena[ARENA_SZ2];

    const int tid = threadIdx.x;
    const int lane = tid & 63, wid = tid >> 6;   // 8 waves
    const int l15 = lane & 15, quad = lane >> 4;
    const int ms = wid & 1, ns = wid >> 1;       // node half x channel quarter

    const int g = blockIdx.x & 255, branch = blockIdx.x >> 8;

    const float* Xsrc = (branch ? fc_x : sc_x) + (size_t)g * NPG * 200;  // 160,000 B
    const int*   ei   = branch ? fc_ei : sc_ei;
    const unsigned short* W1 = Wall + (size_t)branch * W1SZ;
    const unsigned short* W2 = Wall + (size_t)2 * W1SZ + (size_t)branch * W2SZ;

    unsigned int* cnt = (unsigned int*)(arena + CNTOFF);
    float* invdeg = (float*)(arena + IDGOFF);

    // ---- front-end step 1: zero cnt[10000]
    for (int q = tid; q < 10000; q += 512) cnt[q] = 0u;
    __syncthreads();

    // ---- step 2: edge atomics + X fp32 -> bf16 staging into [0,80000)
    {
        const int ebase = g * EPG_;
        for (int i = tid; i < EPG_; i += 512) {
            int src = ei[ebase + i];
            int dst = ei[E_T + ebase + i];
            int idx = (dst - g * NPG) * NPG + (src - g * NPG);
            atomicAdd(&cnt[idx >> 2], 1u << ((idx & 3) * 8));
        }
        // X: 10,000 fp32 dwordx4 chunks -> 8B bf16 each, linear layout
        short* xb = (short*)arena;
#pragma unroll
        for (int j = 0; j < 20; ++j) {
            int i = j * 512 + tid;
            if (i < 10000) {
                float4 a = *(const float4*)(Xsrc + (size_t)i * 4);
                unsigned int lo = (unsigned)f2bf(a.x) | ((unsigned)f2bf(a.y) << 16);
                unsigned int hi = (unsigned)f2bf(a.z) | ((unsigned)f2bf(a.w) << 16);
                uint2 o; o.x = lo; o.y = hi;
                *(uint2*)(xb + (size_t)i * 4) = o;
            }
        }
    }
    __syncthreads();

    // ---- step 3: invdeg[200]
    if (tid < NPG) {
        unsigned int s = 0;
        for (int w = 0; w < 50; ++w) {
            unsigned int v = cnt[tid * 50 + w];
            s += (v & 0xFFu) + ((v >> 8) & 0xFFu) + ((v >> 16) & 0xFFu) + ((v >> 24) & 0xFFu);
        }
        invdeg[tid] = 1.0f / fmaxf((float)s, 1.0f);
    }
    __syncthreads();

    int nrow[7];
#pragma unroll
    for (int mt = 0; mt < 7; ++mt) {
        int s = (ms * 7 + mt) * 16 + l15;
        nrow[mt] = (s > NPG - 1) ? (NPG - 1) : s;   // clamp; killed downstream
    }
    int wrow[2];
#pragma unroll
    for (int nt = 0; nt < 2; ++nt)
        wrow[nt] = (ns * 2 + nt) * 16 + l15;        // ch row 0..127

    // barrier-free agg: acc += Tt x Af, 7 pure-LDS K-steps
    auto AGG = [&](f32x4 (&acc)[2][7]) {
        const short* Tt = (const short*)(arena + TT2OFF);
        const short* Af = (const short*)arena;
#pragma unroll
        for (int ki = 0; ki < 7; ++ki) {
            const int k0 = ki * 32 + quad * 8;
            short8 tf[2];
#pragma unroll
            for (int ct = 0; ct < 2; ++ct)
                tf[ct] = *(const short8*)&Tt[wrow[ct] * TTP + k0];
            short8 afr[7];
#pragma unroll
            for (int dt = 0; dt < 7; ++dt)
                afr[dt] = *(const short8*)&Af[nrow[dt] * AFP + k0];
#pragma unroll
            for (int ct = 0; ct < 2; ++ct)
#pragma unroll
                for (int dt = 0; dt < 7; ++dt)
                    acc[ct][dt] = __builtin_amdgcn_mfma_f32_16x16x32_bf16(
                        tf[ct], afr[dt], acc[ct][dt], 0, 0, 0);
        }
    };

    // T write: acc[m=s][n=c] -> Tt [c 128][s pad 224] at TT2OFF, cols>=200 zero
    auto WRITE_T = [&](f32x4 (&acc)[7][2]) {
        short* Tt = (short*)(arena + TT2OFF);
#pragma unroll
        for (int mt = 0; mt < 7; ++mt) {
            int s0 = (ms * 7 + mt) * 16 + quad * 4;
#pragma unroll
            for (int nt = 0; nt < 2; ++nt) {
                int c = (ns * 2 + nt) * 16 + l15;
                ushort4 o;
                unsigned short* po = (unsigned short*)&o;
#pragma unroll
                for (int r = 0; r < 4; ++r)
                    po[r] = (s0 + r < NPG) ? f2bf(acc[mt][nt][r]) : (unsigned short)0;
                *(ushort4*)&Tt[c * TTP + s0] = o;
            }
        }
    };

    // ================= L1 =================
    {
        f32x4 accT[7][2], accH[2][7];
#pragma unroll
        for (int mt = 0; mt < 7; ++mt)
#pragma unroll
            for (int nt = 0; nt < 2; ++nt)
#pragma unroll
                for (int r = 0; r < 4; ++r) { accT[mt][nt][r] = 0.0f; accH[nt][mt][r] = 0.0f; }

        // phase 2: merged transform + root (X from LDS pitch 400B, W1 direct)
#pragma unroll
        for (int ki = 0; ki < 7; ++ki) {
            int cch = ki * 4 + quad;
            if (cch > 24) cch = 24;                 // never read past staged row
            short8 xf[7];
#pragma unroll
            for (int mt = 0; mt < 7; ++mt)
                xf[mt] = *(const short8*)(arena + nrow[mt] * 400 + cch * 16);
            const int kb = ki * 32 + quad * 8;
            short8 wr[2], wo[2];
#pragma unroll
            for (int nt = 0; nt < 2; ++nt) {
                wr[nt] = *(const short8*)&W1[(size_t)wrow[nt] * KP1 + kb];
                wo[nt] = *(const short8*)&W1[(size_t)(128 + wrow[nt]) * KP1 + kb];
            }
#pragma unroll
            for (int mt = 0; mt < 7; ++mt)
#pragma unroll
                for (int nt = 0; nt < 2; ++nt)
                    accT[mt][nt] = __builtin_amdgcn_mfma_f32_16x16x32_bf16(
                        xf[mt], wr[nt], accT[mt][nt], 0, 0, 0);
#pragma unroll
            for (int nt = 0; nt < 2; ++nt)
#pragma unroll
                for (int mt = 0; mt < 7; ++mt)
                    accH[nt][mt] = __builtin_amdgcn_mfma_f32_16x16x32_bf16(
                        wo[nt], xf[mt], accH[nt][mt], 0, 0, 0);
        }

        __syncthreads();   // F2: X dead everywhere; cnt+invdeg complete

        // EXPAND_ALL: Af[200][AFP], chunks 0..27 (k>=200 zero), over dead X.
        {
            short* Af = (short*)arena;
#pragma unroll
            for (int j = 0; j < 22; ++j) {
                int w = j * 512 + tid;              // 11200 uint2 writes
                if (w < 11200) {
                    int row = w / 56, wj = w - row * 56;   // wj 0..55
                    unsigned int lo = 0u, hi = 0u;
                    if (wj < 50) {                  // k0=wj*4 < 200
                        unsigned int cw = cnt[row * 50 + wj];
                        float inv = invdeg[row];
                        unsigned short b0 = f2bf((float)(cw & 0xFFu) * inv);
                        unsigned short b1 = f2bf((float)((cw >> 8) & 0xFFu) * inv);
                        unsigned short b2 = f2bf((float)((cw >> 16) & 0xFFu) * inv);
                        unsigned short b3 = f2bf((float)((cw >> 24) & 0xFFu) * inv);
                        lo = (unsigned)b0 | ((unsigned)b1 << 16);
                        hi = (unsigned)b2 | ((unsigned)b3 << 16);
                    }
                    uint2 o; o.x = lo; o.y = hi;
                    *(uint2*)(Af + row * AFP + wj * 4) = o;
                }
            }
            if (tid < 256) ((float*)(arena + ZSOFF))[tid] = 0.0f;   // zsum1|zsum2
        }
        __syncthreads();   // F3: Af + zsum visible; cnt+invdeg dead

        WRITE_T(accT);     // Tt over dead cnt region
        __syncthreads();   // F4: Tt visible

        AGG(accH);         // barrier-free
        __syncthreads();   // F5: all waves done reading Tt (h will overwrite)

        // epilogue: relu+bias, pool -> zsum1, h -> LDS at TT2OFF pitch 136
        const float* brel = branch ? f1b : s1b;
        float* zs1 = (float*)(arena + ZSOFF);
        short* hb = (short*)(arena + TT2OFF);
#pragma unroll
        for (int ct = 0; ct < 2; ++ct) {
            const int c0 = (ns * 2 + ct) * 16 + quad * 4;
            float bb[4], part[4];
#pragma unroll
            for (int r = 0; r < 4; ++r) { bb[r] = brel[c0 + r]; part[r] = 0.0f; }
#pragma unroll
            for (int dt = 0; dt < 7; ++dt) {
                const int d = (ms * 7 + dt) * 16 + l15;
                if (d < NPG) {
                    ushort4 o;
                    unsigned short* po = (unsigned short*)&o;
#pragma unroll
                    for (int r = 0; r < 4; ++r) {
                        float v = fmaxf(accH[ct][dt][r] + bb[r], 0.0f);
                        part[r] += v;
                        po[r] = f2bf(v);
                    }
                    *(ushort4*)&hb[d * HP + c0] = o;
                }
            }
#pragma unroll
            for (int r = 0; r < 4; ++r) {
                float v = part[r];
                v += __shfl_xor(v, 1);
                v += __shfl_xor(v, 2);
                v += __shfl_xor(v, 4);
                v += __shfl_xor(v, 8);
                if (l15 == 0) atomicAdd(&zs1[c0 + r], v);
            }
        }
        __syncthreads();   // F6: h + zsum1 final
        if (tid < 128)
            z[(size_t)g * 512 + branch * 256 + 0 + tid] =
                zs1[tid] * (branch ? 1.0f : (1.0f / 200.0f));
    }

    // ================= L2 =================
    {
        f32x4 accT[7][2], accH[2][7];
#pragma unroll
        for (int mt = 0; mt < 7; ++mt)
#pragma unroll
            for (int nt = 0; nt < 2; ++nt)
#pragma unroll
                for (int r = 0; r < 4; ++r) { accT[mt][nt][r] = 0.0f; accH[nt][mt][r] = 0.0f; }

        // phase 2: h (LDS pitch 272B, chunks 0..15 all real) x W2 (direct)
#pragma unroll
        for (int ki = 0; ki < 4; ++ki) {
            short8 xf[7];
#pragma unroll
            for (int mt = 0; mt < 7; ++mt)
                xf[mt] = *(const short8*)(arena + TT2OFF + nrow[mt] * (HP * 2) + (ki * 4 + quad) * 16);
            const int kb = ki * 32 + quad * 8;
            short8 wr[2], wo[2];
#pragma unroll
            for (int nt = 0; nt < 2; ++nt) {
                wr[nt] = *(const short8*)&W2[(size_t)wrow[nt] * HDIM + kb];
                wo[nt] = *(const short8*)&W2[(size_t)(128 + wrow[nt]) * HDIM + kb];
            }
#pragma unroll
            for (int mt = 0; mt < 7; ++mt)
#pragma unroll
                for (int nt = 0; nt < 2; ++nt)
                    accT[mt][nt] = __builtin_amdgcn_mfma_f32_16x16x32_bf16(
                        xf[mt], wr[nt], accT[mt][nt], 0, 0, 0);
#pragma unroll
            for (int nt = 0; nt < 2; ++nt)
#pragma unroll
                for (int mt = 0; mt < 7; ++mt)
                    accH[nt][mt] = __builtin_amdgcn_mfma_f32_16x16x32_bf16(
                        wo[nt], xf[mt], accH[nt][mt], 0, 0, 0);
        }

        __syncthreads();   // F7: h dead
        WRITE_T(accT);     // Tt2 overwrites h region
        __syncthreads();   // F8: Tt2 visible

        AGG(accH);         // barrier-free; Af still valid

        // epilogue: pool only -> zsum2 (separate region; no Tt-write hazard)
        const float* brel = branch ? f2b : s2b;
        float* zs2 = (float*)(arena + ZSOFF + 512);
#pragma unroll
        for (int ct = 0; ct < 2; ++ct) {
            const int c0 = (ns * 2 + ct) * 16 + quad * 4;
            float bb[4], part[4];
#pragma unroll
            for (int r = 0; r < 4; ++r) { bb[r] = brel[c0 + r]; part[r] = 0.0f; }
#pragma unroll
            for (int dt = 0; dt < 7; ++dt) {
                const int d = (ms * 7 + dt) * 16 + l15;
                if (d < NPG) {
#pragma unroll
                    for (int r = 0; r < 4; ++r)
                        part[r] += fmaxf(accH[ct][dt][r] + bb[r], 0.0f);
                }
            }
#pragma unroll
            for (int r = 0; r < 4; ++r) {
                float v = part[r];
                v += __shfl_xor(v, 1);
                v += __shfl_xor(v, 2);
                v += __shfl_xor(v, 4);
                v += __shfl_xor(v, 8);
                if (l15 == 0) atomicAdd(&zs2[c0 + r], v);
            }
        }
        __syncthreads();   // F9: zsum2 complete
        if (tid < 128)
            z[(size_t)g * 512 + branch * 256 + 128 + tid] =
                zs2[tid] * (branch ? 1.0f : (1.0f / 200.0f));
    }
}

// ---------------------------------------------------------------------------
// MLP head (fp32): z[512] -> relu(lin1)[128] -> relu(lin2)[64] -> lin3[2]
// -> log_softmax. One block per graph.  (unchanged)
// ---------------------------------------------------------------------------
__global__ __launch_bounds__(128) void mlp_kernel(const float* __restrict__ z,
                                                  const float* __restrict__ w1, const float* __restrict__ b1,
                                                  const float* __restrict__ w2, const float* __restrict__ b2,
                                                  const float* __restrict__ w3, const float* __restrict__ b3,
                                                  float* __restrict__ out) {
    __shared__ float zs[512];
    __shared__ float l1[128];
    __shared__ float l2[64];
    __shared__ float logits[2];
    int g = blockIdx.x, t = threadIdx.x;

#pragma unroll
    for (int i = 0; i < 4; ++i) zs[t + 128 * i] = z[(size_t)g * 512 + t + 128 * i];
    __syncthreads();

    float s = b1[t];
#pragma unroll 8
    for (int k = 0; k < 512; ++k) s = fmaf(zs[k], w1[k * 128 + t], s);
    l1[t] = fmaxf(s, 0.0f);
    __syncthreads();

    if (t < 64) {
        float s2 = b2[t];
#pragma unroll 8
        for (int k = 0; k < 128; ++k) s2 = fmaf(l1[k], w2[k * 64 + t], s2);
        l2[t] = fmaxf(s2, 0.0f);
    }
    __syncthreads();

    if (t < 2) {
        float s3 = b3[t];
        for (int k = 0; k < 64; ++k) s3 = fmaf(l2[k], w3[k * 2 + t], s3);
        logits[t] = s3;
    }
    __syncthreads();

    if (t < 2) {
        float m = fmaxf(logits[0], logits[1]);
        float lse = m + logf(expf(logits[0] - m) + expf(logits[1] - m));
        out[(size_t)g * 2 + t] = logits[t] - lse;
    }
}

// ---------------------------------------------------------------------------
extern "C" void kernel_launch(void* const* d_in, const int* in_sizes, int n_in,
                              void* d_out, int out_size, void* d_ws, size_t ws_size,
                              hipStream_t stream) {
    const float* sc_x = (const float*)d_in[0];
    const float* fc_x = (const float*)d_in[1];
    const int* sc_ei  = (const int*)d_in[2];
    const int* fc_ei  = (const int*)d_in[3];
    const float* sc1_wrel = (const float*)d_in[5];
    const float* sc1_brel = (const float*)d_in[6];
    const float* sc1_wroot = (const float*)d_in[7];
    const float* sc2_wrel = (const float*)d_in[8];
    const float* sc2_brel = (const float*)d_in[9];
    const float* sc2_wroot = (const float*)d_in[10];
    const float* fc1_wrel = (const float*)d_in[11];
    const float* fc1_brel = (const float*)d_in[12];
    const float* fc1_wroot = (const float*)d_in[13];
    const float* fc2_wrel = (const float*)d_in[14];
    const float* fc2_brel = (const float*)d_in[15];
    const float* fc2_wroot = (const float*)d_in[16];
    const float* lin1_w = (const float*)d_in[17];
    const float* lin1_b = (const float*)d_in[18];
    const float* lin2_w = (const float*)d_in[19];
    const float* lin2_b = (const float*)d_in[20];
    const float* lin3_w = (const float*)d_in[21];
    const float* lin3_b = (const float*)d_in[22];

    // Workspace: Wb (packed bf16 weights) | z   (<1 MB)
    unsigned short* Wb = (unsigned short*)d_ws;                  // 2*(W1SZ+W2SZ)
    float* z = (float*)(Wb + (size_t)2 * (W1SZ + W2SZ));         // 256*512 fp32

    prep_w_kernel<<<NB_CW, 256, 0, stream>>>(
        sc1_wrel, sc1_wroot, fc1_wrel, fc1_wroot,
        sc2_wrel, sc2_wroot, fc2_wrel, fc2_wroot, Wb);

    fused_kernel<<<512, 512, 0, stream>>>(
        sc_x, fc_x, sc_ei, fc_ei, Wb,
        sc1_brel, fc1_brel, sc2_brel, fc2_brel, z);

    mlp_kernel<<<NG, 128, 0, stream>>>(z, lin1_w, lin1_b, lin2_w, lin2_b,
                                       lin3_w, lin3_b, (float*)d_out);
}

// Round 16
// 234.225 us; speedup vs baseline: 1.2314x; 1.0093x over previous
//
#include <hip/hip_runtime.h>
#include <hip/hip_bf16.h>
#include <math.h>

#define NPG   200                 // nodes per graph
#define HDIM  128
#define NG    256
#define NT_T  (NG * NPG)          // 51200
#define EPG_  3200
#define E_T   (NG * EPG_)         // 819200
#define KP1   224                 // layer-1 K (200) padded to mult of 32 (W pitch)
#define TTP   232                 // Tt LDS pitch (shorts): 29 chunks (mod8=5, spread)
#define AFP   232                 // A'full LDS pitch (shorts): same spread
#define HP    136                 // h LDS pitch (shorts): 17 chunks (mod8=1, spread)
#define W1SZ  (256 * KP1)
#define W2SZ  (256 * HDIM)

// LDS arena (bytes):
//   Af [0,92800) over dead X | Tt/h [92800,152192) over dead cnt+invdeg |
//   cnt u32[10000] [112000,152000) | invdeg f32[200] [152000,152800) |
//   zsum [152960,153984)
#define TT2OFF 92800
#define CNTOFF 112000
#define IDGOFF 152000
#define ZSOFF  152960             // zsum1[128] | zsum2[128] f32
#define ARENA_SZ2 153984

#define NB_CW  ((2 * (W1SZ + W2SZ)) / 256)    // 704

typedef short short8 __attribute__((ext_vector_type(8)));
typedef float f32x4  __attribute__((ext_vector_type(4)));

// HW bf16 conversion (v_cvt_pk_bf16_f32 path, RNE — bit-identical to the old
// add-round-shift trick for finite values).  r15-verified: VALUBusy 24->21,
// absmax unchanged.
__device__ __forceinline__ unsigned short f2bf(float f) {
    union { __hip_bfloat16 b; unsigned short u; } v;
    v.b = __float2bfloat16(f);
    return v.u;
}

// ---------------------------------------------------------------------------
// Prep: W convert ONLY (X convert and adjacency live in the fused kernel).
// Packing identical to all prior rounds: [br0L1|br1L1|br0L2|br1L2], rel|root.
// ---------------------------------------------------------------------------
__global__ __launch_bounds__(256) void prep_w_kernel(
        const float* __restrict__ s1r, const float* __restrict__ s1o,
        const float* __restrict__ f1r, const float* __restrict__ f1o,
        const float* __restrict__ s2r, const float* __restrict__ s2o,
        const float* __restrict__ f2r, const float* __restrict__ f2o,
        unsigned short* __restrict__ wb) {
    int idx = blockIdx.x * 256 + threadIdx.x;
    float v = 0.0f;
    if (idx < 2 * W1SZ) {
        int branch = idx / W1SZ, rem = idx - branch * W1SZ;
        int c = rem / KP1, k = rem - c * KP1;
        const float* wr = branch ? f1r : s1r;
        const float* wo = branch ? f1o : s1o;
        if (k < 200) v = (c < 128) ? wr[(size_t)k * 128 + c] : wo[(size_t)k * 128 + (c - 128)];
    } else {
        int i2 = idx - 2 * W1SZ;
        int branch = i2 / W2SZ, rem = i2 - branch * W2SZ;
        int c = rem / HDIM, k = rem - c * HDIM;
        const float* wr = branch ? f2r : s2r;
        const float* wo = branch ? f2o : s2o;
        v = (c < 128) ? wr[(size_t)k * 128 + c] : wo[(size_t)k * 128 + (c - 128)];
    }
    wb[idx] = f2bf(v);
}

// ---------------------------------------------------------------------------
// Round-22 fused kernel = round-15 (best-verified 236.4 µs) + front-end
// micro-bundle:
//   (1) invdeg barrier DELETED — invdeg/cnt are consumed only by EXPAND
//       (after the F2 __syncthreads); phase2 touches neither.  The barrier
//       only lockstepped 8 waves; now idle threads flow into phase2 while
//       tid<200 finish the serial invdeg scans.
//   (2) edge-index prefetch into registers BEFORE the cnt-zero loop — the
//       ~600-900cy HBM latency hides under zeroing + barrier (atomic adds
//       commute; values identical).
//   (3) cnt zeroing via uint4 (2500 b128 LDS writes vs 10000 b32).
// Everything else verbatim r15.  Output bit-identical.
// ---------------------------------------------------------------------------
__global__ __launch_bounds__(512, 1) void fused_kernel(
        const float* __restrict__ sc_x, const float* __restrict__ fc_x,
        const int* __restrict__ sc_ei, const int* __restrict__ fc_ei,
        const unsigned short* __restrict__ Wall,
        const float* __restrict__ s1b, const float* __restrict__ f1b,
        const float* __restrict__ s2b, const float* __restrict__ f2b,
        float* __restrict__ z) {
    __shared__ __attribute__((aligned(16))) char arena[ARENA_SZ2];

    const int tid = threadIdx.x;
    const int lane = tid & 63, wid = tid >> 6;   // 8 waves
    const int l15 = lane & 15, quad = lane >> 4;
    const int ms = wid & 1, ns = wid >> 1;       // node half x channel quarter

    const int g = blockIdx.x & 255, branch = blockIdx.x >> 8;

    const float* Xsrc = (branch ? fc_x : sc_x) + (size_t)g * NPG * 200;  // 160,000 B
    const int*   ei   = branch ? fc_ei : sc_ei;
    const unsigned short* W1 = Wall + (size_t)branch * W1SZ;
    const unsigned short* W2 = Wall + (size_t)2 * W1SZ + (size_t)branch * W2SZ;

    unsigned int* cnt = (unsigned int*)(arena + CNTOFF);
    float* invdeg = (float*)(arena + IDGOFF);

    // ---- front-end: prefetch edge indices (loads fly during cnt zeroing)
    const int ebase = g * EPG_;
    int e0[7], e1[7];
#pragma unroll
    for (int j = 0; j < 7; ++j) {
        int i = j * 512 + tid;
        if (i < EPG_) {
            e0[j] = ei[ebase + i];
            e1[j] = ei[E_T + ebase + i];
        } else {
            e0[j] = 0; e1[j] = 0;
        }
    }

    // zero cnt[10000] via uint4 (16B-aligned base)
#pragma unroll
    for (int j = 0; j < 5; ++j) {
        int q = j * 512 + tid;
        if (q < 2500) {
            uint4 zz; zz.x = zz.y = zz.z = zz.w = 0u;
            *(uint4*)&cnt[q * 4] = zz;
        }
    }
    __syncthreads();

    // ---- edge atomics (consume prefetched regs) + X fp32->bf16 staging
    {
#pragma unroll
        for (int j = 0; j < 7; ++j) {
            int i = j * 512 + tid;
            if (i < EPG_) {
                int idx = (e1[j] - g * NPG) * NPG + (e0[j] - g * NPG);
                atomicAdd(&cnt[idx >> 2], 1u << ((idx & 3) * 8));
            }
        }
        // X: 10,000 fp32 dwordx4 chunks -> 8B bf16 each, linear layout
        short* xb = (short*)arena;
#pragma unroll
        for (int j = 0; j < 20; ++j) {
            int i = j * 512 + tid;
            if (i < 10000) {
                float4 a = *(const float4*)(Xsrc + (size_t)i * 4);
                unsigned int lo = (unsigned)f2bf(a.x) | ((unsigned)f2bf(a.y) << 16);
                unsigned int hi = (unsigned)f2bf(a.z) | ((unsigned)f2bf(a.w) << 16);
                uint2 o; o.x = lo; o.y = hi;
                *(uint2*)(xb + (size_t)i * 4) = o;
            }
        }
    }
    __syncthreads();

    // ---- invdeg[200] (no trailing barrier: consumed only after F2)
    if (tid < NPG) {
        unsigned int s = 0;
        for (int w = 0; w < 50; ++w) {
            unsigned int v = cnt[tid * 50 + w];
            s += (v & 0xFFu) + ((v >> 8) & 0xFFu) + ((v >> 16) & 0xFFu) + ((v >> 24) & 0xFFu);
        }
        invdeg[tid] = 1.0f / fmaxf((float)s, 1.0f);
    }

    int nrow[7];
#pragma unroll
    for (int mt = 0; mt < 7; ++mt) {
        int s = (ms * 7 + mt) * 16 + l15;
        nrow[mt] = (s > NPG - 1) ? (NPG - 1) : s;   // clamp; killed downstream
    }
    int wrow[2];
#pragma unroll
    for (int nt = 0; nt < 2; ++nt)
        wrow[nt] = (ns * 2 + nt) * 16 + l15;        // ch row 0..127

    // barrier-free agg: acc += Tt x Af, 7 pure-LDS K-steps
    auto AGG = [&](f32x4 (&acc)[2][7]) {
        const short* Tt = (const short*)(arena + TT2OFF);
        const short* Af = (const short*)arena;
#pragma unroll
        for (int ki = 0; ki < 7; ++ki) {
            const int k0 = ki * 32 + quad * 8;
            short8 tf[2];
#pragma unroll
            for (int ct = 0; ct < 2; ++ct)
                tf[ct] = *(const short8*)&Tt[wrow[ct] * TTP + k0];
            short8 afr[7];
#pragma unroll
            for (int dt = 0; dt < 7; ++dt)
                afr[dt] = *(const short8*)&Af[nrow[dt] * AFP + k0];
#pragma unroll
            for (int ct = 0; ct < 2; ++ct)
#pragma unroll
                for (int dt = 0; dt < 7; ++dt)
                    acc[ct][dt] = __builtin_amdgcn_mfma_f32_16x16x32_bf16(
                        tf[ct], afr[dt], acc[ct][dt], 0, 0, 0);
        }
    };

    // T write: acc[m=s][n=c] -> Tt [c 128][s pad 224] at TT2OFF, cols>=200 zero
    auto WRITE_T = [&](f32x4 (&acc)[7][2]) {
        short* Tt = (short*)(arena + TT2OFF);
#pragma unroll
        for (int mt = 0; mt < 7; ++mt) {
            int s0 = (ms * 7 + mt) * 16 + quad * 4;
#pragma unroll
            for (int nt = 0; nt < 2; ++nt) {
                int c = (ns * 2 + nt) * 16 + l15;
                ushort4 o;
                unsigned short* po = (unsigned short*)&o;
#pragma unroll
                for (int r = 0; r < 4; ++r)
                    po[r] = (s0 + r < NPG) ? f2bf(acc[mt][nt][r]) : (unsigned short)0;
                *(ushort4*)&Tt[c * TTP + s0] = o;
            }
        }
    };

    // ================= L1 =================
    {
        f32x4 accT[7][2], accH[2][7];
#pragma unroll
        for (int mt = 0; mt < 7; ++mt)
#pragma unroll
            for (int nt = 0; nt < 2; ++nt)
#pragma unroll
                for (int r = 0; r < 4; ++r) { accT[mt][nt][r] = 0.0f; accH[nt][mt][r] = 0.0f; }

        // phase 2: merged transform + root (X from LDS pitch 400B, W1 direct)
#pragma unroll
        for (int ki = 0; ki < 7; ++ki) {
            int cch = ki * 4 + quad;
            if (cch > 24) cch = 24;                 // never read past staged row
            short8 xf[7];
#pragma unroll
            for (int mt = 0; mt < 7; ++mt)
                xf[mt] = *(const short8*)(arena + nrow[mt] * 400 + cch * 16);
            const int kb = ki * 32 + quad * 8;
            short8 wr[2], wo[2];
#pragma unroll
            for (int nt = 0; nt < 2; ++nt) {
                wr[nt] = *(const short8*)&W1[(size_t)wrow[nt] * KP1 + kb];
                wo[nt] = *(const short8*)&W1[(size_t)(128 + wrow[nt]) * KP1 + kb];
            }
#pragma unroll
            for (int mt = 0; mt < 7; ++mt)
#pragma unroll
                for (int nt = 0; nt < 2; ++nt)
                    accT[mt][nt] = __builtin_amdgcn_mfma_f32_16x16x32_bf16(
                        xf[mt], wr[nt], accT[mt][nt], 0, 0, 0);
#pragma unroll
            for (int nt = 0; nt < 2; ++nt)
#pragma unroll
                for (int mt = 0; mt < 7; ++mt)
                    accH[nt][mt] = __builtin_amdgcn_mfma_f32_16x16x32_bf16(
                        wo[nt], xf[mt], accH[nt][mt], 0, 0, 0);
        }

        __syncthreads();   // F2: X dead everywhere; cnt+invdeg complete

        // EXPAND_ALL: Af[200][AFP], chunks 0..27 (k>=200 zero), over dead X.
        {
            short* Af = (short*)arena;
#pragma unroll
            for (int j = 0; j < 22; ++j) {
                int w = j * 512 + tid;              // 11200 uint2 writes
                if (w < 11200) {
                    int row = w / 56, wj = w - row * 56;   // wj 0..55
                    unsigned int lo = 0u, hi = 0u;
                    if (wj < 50) {                  // k0=wj*4 < 200
                        unsigned int cw = cnt[row * 50 + wj];
                        float inv = invdeg[row];
                        unsigned short b0 = f2bf((float)(cw & 0xFFu) * inv);
                        unsigned short b1 = f2bf((float)((cw >> 8) & 0xFFu) * inv);
                        unsigned short b2 = f2bf((float)((cw >> 16) & 0xFFu) * inv);
                        unsigned short b3 = f2bf((float)((cw >> 24) & 0xFFu) * inv);
                        lo = (unsigned)b0 | ((unsigned)b1 << 16);
                        hi = (unsigned)b2 | ((unsigned)b3 << 16);
                    }
                    uint2 o; o.x = lo; o.y = hi;
                    *(uint2*)(Af + row * AFP + wj * 4) = o;
                }
            }
            if (tid < 256) ((float*)(arena + ZSOFF))[tid] = 0.0f;   // zsum1|zsum2
        }
        __syncthreads();   // F3: Af + zsum visible; cnt+invdeg dead

        WRITE_T(accT);     // Tt over dead cnt region
        __syncthreads();   // F4: Tt visible

        AGG(accH);         // barrier-free
        __syncthreads();   // F5: all waves done reading Tt (h will overwrite)

        // epilogue: relu+bias, pool -> zsum1, h -> LDS at TT2OFF pitch 136
        const float* brel = branch ? f1b : s1b;
        float* zs1 = (float*)(arena + ZSOFF);
        short* hb = (short*)(arena + TT2OFF);
#pragma unroll
        for (int ct = 0; ct < 2; ++ct) {
            const int c0 = (ns * 2 + ct) * 16 + quad * 4;
            float bb[4], part[4];
#pragma unroll
            for (int r = 0; r < 4; ++r) { bb[r] = brel[c0 + r]; part[r] = 0.0f; }
#pragma unroll
            for (int dt = 0; dt < 7; ++dt) {
                const int d = (ms * 7 + dt) * 16 + l15;
                if (d < NPG) {
                    ushort4 o;
                    unsigned short* po = (unsigned short*)&o;
#pragma unroll
                    for (int r = 0; r < 4; ++r) {
                        float v = fmaxf(accH[ct][dt][r] + bb[r], 0.0f);
                        part[r] += v;
                        po[r] = f2bf(v);
                    }
                    *(ushort4*)&hb[d * HP + c0] = o;
                }
            }
#pragma unroll
            for (int r = 0; r < 4; ++r) {
                float v = part[r];
                v += __shfl_xor(v, 1);
                v += __shfl_xor(v, 2);
                v += __shfl_xor(v, 4);
                v += __shfl_xor(v, 8);
                if (l15 == 0) atomicAdd(&zs1[c0 + r], v);
            }
        }
        __syncthreads();   // F6: h + zsum1 final
        if (tid < 128)
            z[(size_t)g * 512 + branch * 256 + 0 + tid] =
                zs1[tid] * (branch ? 1.0f : (1.0f / 200.0f));
    }

    // ================= L2 =================
    {
        f32x4 accT[7][2], accH[2][7];
#pragma unroll
        for (int mt = 0; mt < 7; ++mt)
#pragma unroll
            for (int nt = 0; nt < 2; ++nt)
#pragma unroll
                for (int r = 0; r < 4; ++r) { accT[mt][nt][r] = 0.0f; accH[nt][mt][r] = 0.0f; }

        // phase 2: h (LDS pitch 272B, chunks 0..15 all real) x W2 (direct)
#pragma unroll
        for (int ki = 0; ki < 4; ++ki) {
            short8 xf[7];
#pragma unroll
            for (int mt = 0; mt < 7; ++mt)
                xf[mt] = *(const short8*)(arena + TT2OFF + nrow[mt] * (HP * 2) + (ki * 4 + quad) * 16);
            const int kb = ki * 32 + quad * 8;
            short8 wr[2], wo[2];
#pragma unroll
            for (int nt = 0; nt < 2; ++nt) {
                wr[nt] = *(const short8*)&W2[(size_t)wrow[nt] * HDIM + kb];
                wo[nt] = *(const short8*)&W2[(size_t)(128 + wrow[nt]) * HDIM + kb];
            }
#pragma unroll
            for (int mt = 0; mt < 7; ++mt)
#pragma unroll
                for (int nt = 0; nt < 2; ++nt)
                    accT[mt][nt] = __builtin_amdgcn_mfma_f32_16x16x32_bf16(
                        xf[mt], wr[nt], accT[mt][nt], 0, 0, 0);
#pragma unroll
            for (int nt = 0; nt < 2; ++nt)
#pragma unroll
                for (int mt = 0; mt < 7; ++mt)
                    accH[nt][mt] = __builtin_amdgcn_mfma_f32_16x16x32_bf16(
                        wo[nt], xf[mt], accH[nt][mt], 0, 0, 0);
        }

        __syncthreads();   // F7: h dead
        WRITE_T(accT);     // Tt2 overwrites h region
        __syncthreads();   // F8: Tt2 visible

        AGG(accH);         // barrier-free; Af still valid

        // epilogue: pool only -> zsum2 (separate region; no Tt-write hazard)
        const float* brel = branch ? f2b : s2b;
        float* zs2 = (float*)(arena + ZSOFF + 512);
#pragma unroll
        for (int ct = 0; ct < 2; ++ct) {
            const int c0 = (ns * 2 + ct) * 16 + quad * 4;
            float bb[4], part[4];
#pragma unroll
            for (int r = 0; r < 4; ++r) { bb[r] = brel[c0 + r]; part[r] = 0.0f; }
#pragma unroll
            for (int dt = 0; dt < 7; ++dt) {
                const int d = (ms * 7 + dt) * 16 + l15;
                if (d < NPG) {
#pragma unroll
                    for (int r = 0; r < 4; ++r)
                        part[r] += fmaxf(accH[ct][dt][r] + bb[r], 0.0f);
                }
            }
#pragma unroll
            for (int r = 0; r < 4; ++r) {
                float v = part[r];
                v += __shfl_xor(v, 1);
                v += __shfl_xor(v, 2);
                v += __shfl_xor(v, 4);
                v += __shfl_xor(v, 8);
                if (l15 == 0) atomicAdd(&zs2[c0 + r], v);
            }
        }
        __syncthreads();   // F9: zsum2 complete
        if (tid < 128)
            z[(size_t)g * 512 + branch * 256 + 128 + tid] =
                zs2[tid] * (branch ? 1.0f : (1.0f / 200.0f));
    }
}

// ---------------------------------------------------------------------------
// MLP head (fp32): z[512] -> relu(lin1)[128] -> relu(lin2)[64] -> lin3[2]
// -> log_softmax. One block per graph.  (unchanged)
// ---------------------------------------------------------------------------
__global__ __launch_bounds__(128) void mlp_kernel(const float* __restrict__ z,
                                                  const float* __restrict__ w1, const float* __restrict__ b1,
                                                  const float* __restrict__ w2, const float* __restrict__ b2,
                                                  const float* __restrict__ w3, const float* __restrict__ b3,
                                                  float* __restrict__ out) {
    __shared__ float zs[512];
    __shared__ float l1[128];
    __shared__ float l2[64];
    __shared__ float logits[2];
    int g = blockIdx.x, t = threadIdx.x;

#pragma unroll
    for (int i = 0; i < 4; ++i) zs[t + 128 * i] = z[(size_t)g * 512 + t + 128 * i];
    __syncthreads();

    float s = b1[t];
#pragma unroll 8
    for (int k = 0; k < 512; ++k) s = fmaf(zs[k], w1[k * 128 + t], s);
    l1[t] = fmaxf(s, 0.0f);
    __syncthreads();

    if (t < 64) {
        float s2 = b2[t];
#pragma unroll 8
        for (int k = 0; k < 128; ++k) s2 = fmaf(l1[k], w2[k * 64 + t], s2);
        l2[t] = fmaxf(s2, 0.0f);
    }
    __syncthreads();

    if (t < 2) {
        float s3 = b3[t];
        for (int k = 0; k < 64; ++k) s3 = fmaf(l2[k], w3[k * 2 + t], s3);
        logits[t] = s3;
    }
    __syncthreads();

    if (t < 2) {
        float m = fmaxf(logits[0], logits[1]);
        float lse = m + logf(expf(logits[0] - m) + expf(logits[1] - m));
        out[(size_t)g * 2 + t] = logits[t] - lse;
    }
}

// ---------------------------------------------------------------------------
extern "C" void kernel_launch(void* const* d_in, const int* in_sizes, int n_in,
                              void* d_out, int out_size, void* d_ws, size_t ws_size,
                              hipStream_t stream) {
    const float* sc_x = (const float*)d_in[0];
    const float* fc_x = (const float*)d_in[1];
    const int* sc_ei  = (const int*)d_in[2];
    const int* fc_ei  = (const int*)d_in[3];
    const float* sc1_wrel = (const float*)d_in[5];
    const float* sc1_brel = (const float*)d_in[6];
    const float* sc1_wroot = (const float*)d_in[7];
    const float* sc2_wrel = (const float*)d_in[8];
    const float* sc2_brel = (const float*)d_in[9];
    const float* sc2_wroot = (const float*)d_in[10];
    const float* fc1_wrel = (const float*)d_in[11];
    const float* fc1_brel = (const float*)d_in[12];
    const float* fc1_wroot = (const float*)d_in[13];
    const float* fc2_wrel = (const float*)d_in[14];
    const float* fc2_brel = (const float*)d_in[15];
    const float* fc2_wroot = (const float*)d_in[16];
    const float* lin1_w = (const float*)d_in[17];
    const float* lin1_b = (const float*)d_in[18];
    const float* lin2_w = (const float*)d_in[19];
    const float* lin2_b = (const float*)d_in[20];
    const float* lin3_w = (const float*)d_in[21];
    const float* lin3_b = (const float*)d_in[22];

    // Workspace: Wb (packed bf16 weights) | z   (<1 MB)
    unsigned short* Wb = (unsigned short*)d_ws;                  // 2*(W1SZ+W2SZ)
    float* z = (float*)(Wb + (size_t)2 * (W1SZ + W2SZ));         // 256*512 fp32

    prep_w_kernel<<<NB_CW, 256, 0, stream>>>(
        sc1_wrel, sc1_wroot, fc1_wrel, fc1_wroot,
        sc2_wrel, sc2_wroot, fc2_wrel, fc2_wroot, Wb);

    fused_kernel<<<512, 512, 0, stream>>>(
        sc_x, fc_x, sc_ei, fc_ei, Wb,
        sc1_brel, fc1_brel, sc2_brel, fc2_brel, z);

    mlp_kernel<<<NG, 128, 0, stream>>>(z, lin1_w, lin1_b, lin2_w, lin2_b,
                                       lin3_w, lin3_b, (float*)d_out);
}